// Round 9
// baseline (785.887 us; speedup 1.0000x reference)
//
#include <hip/hip_runtime.h>
#include <hip/hip_bf16.h>
#include <math.h>

#define BB 8
#define TT 256
#define DD 256
#define HH 8
#define DHH 32
#define LL 4
#define DFF 1024
#define QTILE 16

#define RBF_DELTA 0.05039370078740158f
#define RBF_INVGAP 20.0f

typedef __attribute__((ext_vector_type(8))) short short8v;
typedef __attribute__((ext_vector_type(4))) short short4v;
typedef __attribute__((ext_vector_type(4))) float f32x4;

__device__ __forceinline__ ushort f2bf(float x) {
    __hip_bfloat16 h = __float2bfloat16(x);
    return *reinterpret_cast<ushort*>(&h);
}

// ---------------- weight f32 -> bf16 convert -----------------
__global__ void convert_bf16_kernel(const float* __restrict__ in,
                                    ushort* __restrict__ out, int n4) {
    int i = blockIdx.x * blockDim.x + threadIdx.x;
    if (i < n4) {
        float4 v = reinterpret_cast<const float4*>(in)[i];
        short4v o;
        o.x = (short)f2bf(v.x); o.y = (short)f2bf(v.y);
        o.z = (short)f2bf(v.z); o.w = (short)f2bf(v.w);
        reinterpret_cast<short4v*>(out)[i] = o;
    }
}

// ---------------- temb ----------------
__global__ void temb_kernel(const float* __restrict__ timestep,
                            const float* __restrict__ t_w1, const float* __restrict__ t_b1,
                            const float* __restrict__ t_w2, const float* __restrict__ t_b2,
                            float* __restrict__ temb_out) {
    __shared__ float s0[128], s1[128];
    int b = blockIdx.x, j = threadIdx.x;
    float ts = timestep[b];
    const float LOG1E4 = 9.210340371976184f;
    if (j < 64) {
        float f = expf(-LOG1E4 * (float)j / 64.f);
        s0[j] = cosf(ts * f);
    } else {
        int i = j - 64;
        float f = expf(-LOG1E4 * (float)i / 64.f);
        s0[j] = sinf(ts * f);
    }
    __syncthreads();
    float acc = t_b1[j];
    for (int i = 0; i < 128; i++) acc += s0[i] * t_w1[i * 128 + j];
    acc = acc / (1.f + expf(-acc));
    s1[j] = acc;
    __syncthreads();
    float acc2 = t_b2[j];
    for (int i = 0; i < 128; i++) acc2 += s1[i] * t_w2[i * 128 + j];
    temb_out[b * 128 + j] = acc2;
}

// ---------------- embedding ----------------
__global__ void embed_kernel(const int* __restrict__ src, const float* __restrict__ emb,
                             float* __restrict__ x) {
    int r = blockIdx.x, d = threadIdx.x;
    x[r * DD + d] = emb[src[r] * DD + d];
}

// ---------------- LayerNorm (templated output dtype) ----------------
template <int OUT_BF16>
__global__ void ln_kernel(const float* __restrict__ in, const float* __restrict__ g,
                          const float* __restrict__ bta, void* __restrict__ out) {
    __shared__ float red[8];
    __shared__ float mv[2];
    int r = blockIdx.x, t = threadIdx.x;
    float v = in[r * DD + t];
    float s = v, s2 = v * v;
    for (int off = 32; off > 0; off >>= 1) {
        s += __shfl_xor(s, off);
        s2 += __shfl_xor(s2, off);
    }
    int w = t >> 6;
    if ((t & 63) == 0) { red[w] = s; red[4 + w] = s2; }
    __syncthreads();
    if (t == 0) {
        float S = red[0] + red[1] + red[2] + red[3];
        float S2 = red[4] + red[5] + red[6] + red[7];
        float m = S * (1.f / 256.f);
        float var = S2 * (1.f / 256.f) - m * m;
        mv[0] = m; mv[1] = rsqrtf(var + 1e-6f);
    }
    __syncthreads();
    float o = (v - mv[0]) * mv[1] * g[t] + bta[t];
    if (OUT_BF16) ((ushort*)out)[r * DD + t] = f2bf(o);
    else          ((float*)out)[r * DD + t] = o;
}

// ---------------- bf16 MFMA GEMM ----------------
// C[M,N] = (A[M,K](bf16) @ W[K,N](bf16) + bias)*scale (+relu) (+resid f32)
// block: 128 thr (2 waves), tile M=32 (wave w: rows w*16..), N=64 (4 nblk), BK=64.
// LDS: As[32][64] bf16 row-major, Bs_t[64(n)][64(k)] bf16; XOR swizzle
// byte ^= (row&7)<<4 applied to both write and read.
__device__ __forceinline__ void gemm_mfma_body(
    const ushort* __restrict__ A, const ushort* __restrict__ W,
    const float* __restrict__ bias, const float* __restrict__ resid,
    void* __restrict__ out, int N, int K, float scale, int RELU, int OUT_BF16) {
    __shared__ __align__(16) ushort As[32 * 64];
    __shared__ __align__(16) ushort Bs[64 * 64];
    int tid = threadIdx.x;
    int w = tid >> 6, lane = tid & 63;
    int m0 = blockIdx.y * 32, n0 = blockIdx.x * 64;

    f32x4 acc[4] = {f32x4{0,0,0,0}, f32x4{0,0,0,0}, f32x4{0,0,0,0}, f32x4{0,0,0,0}};

    int bn = tid & 63;           // B-stage n
    int bkg = tid >> 6;          // B-stage k group (0/1)

    for (int k0 = 0; k0 < K; k0 += 64) {
        // stage A: 32 rows x 64 k; 2 iters of 16B chunks
#pragma unroll
        for (int it = 0; it < 2; it++) {
            int idx = it * 128 + tid;
            int r = idx >> 3, k8 = idx & 7;         // r 0..31, k8 0..7
            short8v av = *reinterpret_cast<const short8v*>(&A[(m0 + r) * K + k0 + k8 * 8]);
            int dstb = r * 128 + ((k8 * 16) ^ ((r & 7) << 4));
            *reinterpret_cast<short8v*>((char*)As + dstb) = av;
        }
        // stage B transposed: Bs_t[n][k]; 8 iters, 4 strided-k reads each
#pragma unroll
        for (int it = 0; it < 8; it++) {
            int kk0 = it * 8 + bkg * 4;
            short4v bv;
            bv.x = (short)W[(k0 + kk0 + 0) * N + n0 + bn];
            bv.y = (short)W[(k0 + kk0 + 1) * N + n0 + bn];
            bv.z = (short)W[(k0 + kk0 + 2) * N + n0 + bn];
            bv.w = (short)W[(k0 + kk0 + 3) * N + n0 + bn];
            int dstb = bn * 128 + ((kk0 * 2) ^ ((bn & 7) << 4));
            *reinterpret_cast<short4v*>((char*)Bs + dstb) = bv;
        }
        __syncthreads();
        int arow = w * 16 + (lane & 15);
        int koff0 = (lane >> 4) * 16;
#pragma unroll
        for (int ksub = 0; ksub < 2; ksub++) {
            int kb = ksub * 64 + koff0;
            short8v a = *reinterpret_cast<const short8v*>(
                (char*)As + arow * 128 + (kb ^ ((arow & 7) << 4)));
#pragma unroll
            for (int nb = 0; nb < 4; nb++) {
                int nrow = nb * 16 + (lane & 15);
                short8v bfr = *reinterpret_cast<const short8v*>(
                    (char*)Bs + nrow * 128 + (kb ^ ((nrow & 7) << 4)));
                acc[nb] = __builtin_amdgcn_mfma_f32_16x16x32_bf16(a, bfr, acc[nb], 0, 0, 0);
            }
        }
        __syncthreads();
    }
    // epilogue: D row=(lane>>4)*4+i, col=lane&15
    int col = lane & 15;
#pragma unroll
    for (int nb = 0; nb < 4; nb++) {
        int n = n0 + nb * 16 + col;
        float bia = bias[n];
#pragma unroll
        for (int i = 0; i < 4; i++) {
            int m = m0 + w * 16 + (lane >> 4) * 4 + i;
            float v = (acc[nb][i] + bia) * scale;
            if (RELU) v = fmaxf(v, 0.f);
            if (resid) v += resid[m * N + n];
            if (OUT_BF16) ((ushort*)out)[m * N + n] = f2bf(v);
            else          ((float*)out)[m * N + n] = v;
        }
    }
}

template <int RELU, int OUT_BF16>
__global__ __launch_bounds__(128) void gemm_bf16(
    const ushort* __restrict__ A, const ushort* __restrict__ W,
    const float* __restrict__ bias, const float* __restrict__ resid,
    void* __restrict__ out, int N, int K, float scale) {
    gemm_mfma_body(A, W, bias, resid, out, N, K, scale, RELU, OUT_BF16);
}

// fused Q/K/V via blockIdx.z
__global__ __launch_bounds__(128) void qkv_bf16(
    const ushort* __restrict__ A,
    const ushort* __restrict__ Wq, const float* __restrict__ bq, float* __restrict__ qo,
    const ushort* __restrict__ Wk, const float* __restrict__ bk, float* __restrict__ ko,
    const ushort* __restrict__ Wv, const float* __restrict__ bv, float* __restrict__ vo,
    float qscale) {
    int z = blockIdx.z;
    const ushort* W = (z == 0) ? Wq : (z == 1) ? Wk : Wv;
    const float* bi = (z == 0) ? bq : (z == 1) ? bk : bv;
    float* o = (z == 0) ? qo : (z == 1) ? ko : vo;
    float sc = (z == 0) ? qscale : 1.f;
    gemm_mfma_body(A, W, bi, nullptr, o, DD, DD, sc, 0, 0);
}

// ---------------- fused attention (unchanged math; bf16 ctx out) -----------
__global__ __launch_bounds__(256, 2) void attn_kernel(
    const float* __restrict__ qbuf, const float* __restrict__ kbuf,
    const float* __restrict__ vbuf, const float* __restrict__ u,
    const float* __restrict__ v, const float* __restrict__ temb,
    const float* __restrict__ bond, const int* __restrict__ lengths,
    ushort* __restrict__ ctx) {
    __shared__ float KV[256][33];
    __shared__ float sc[QTILE][257];
    __shared__ float qu_s[QTILE][32], qv_s[QTILE][32];
    __shared__ float tq[QTILE];
    __shared__ float temb_s[32];

    int qt = blockIdx.x;
    int h  = blockIdx.y;
    int b  = blockIdx.z;
    int t  = threadIdx.x;
    int len = lengths[b];
    int q0 = qt * QTILE;

    for (int e = t; e < QTILE * 32; e += 256) {
        int q = e >> 5, dh = e & 31;
        float qs = qbuf[(b * TT + q0 + q) * DD + h * 32 + dh];
        qu_s[q][dh] = qs + u[h * 32 + dh];
        qv_s[q][dh] = qs + v[h * 32 + dh];
    }
    if (t < 32) temb_s[t] = (h >= 4) ? temb[b * 128 + (h - 4) * 32 + t] : 0.f;
    for (int e = t; e < 256 * 32; e += 256) {
        int k = e >> 5, dh = e & 31;
        KV[k][dh] = kbuf[(b * TT + k) * DD + h * 32 + dh];
    }
    __syncthreads();

    if (t < QTILE) {
        float a = 0.f;
#pragma unroll
        for (int j = 0; j < 32; j++) a += qv_s[t][j] * temb_s[j];
        tq[t] = a;
    }
    __syncthreads();

    {
        int k = t;
        bool kvalid = k < len;
        float c0 = (float)(h * 32) * RBF_DELTA;
        for (int q = 0; q < QTILE; q++) {
            float s;
            if (!kvalid) {
                s = -1e18f;
            } else {
                float accA = 0.f;
#pragma unroll
                for (int dh = 0; dh < 32; dh++) accA += qu_s[q][dh] * KV[k][dh];
                float accB;
                if (h < 4) {
                    accB = 0.f;
                    if (q0 + q < len) {
                        float d = bond[(b * TT + q0 + q) * TT + k];
#pragma unroll
                        for (int j = 0; j < 32; j++) {
                            float diff = d - (c0 + j * RBF_DELTA);
                            accB += qv_s[q][j] * __expf(-diff * diff * RBF_INVGAP);
                        }
                    }
                } else {
                    accB = tq[q];
                }
                s = accA + accB;
            }
            sc[q][k] = s;
        }
    }
    __syncthreads();

    {
        int r = t >> 4, j = t & 15;
        float vals[16];
        float mx = -1e30f;
#pragma unroll
        for (int i = 0; i < 16; i++) {
            vals[i] = sc[r][j + 16 * i];
            mx = fmaxf(mx, vals[i]);
        }
        for (int off = 8; off > 0; off >>= 1) mx = fmaxf(mx, __shfl_xor(mx, off));
        float sum = 0.f;
#pragma unroll
        for (int i = 0; i < 16; i++) {
            float e = __expf(vals[i] - mx);
            vals[i] = e; sum += e;
        }
        for (int off = 8; off > 0; off >>= 1) sum += __shfl_xor(sum, off);
        float inv = 1.f / sum;
#pragma unroll
        for (int i = 0; i < 16; i++) sc[r][j + 16 * i] = vals[i] * inv;
    }
    for (int e = t; e < 256 * 32; e += 256) {
        int k2 = e >> 5, dh = e & 31;
        KV[k2][dh] = vbuf[(b * TT + k2) * DD + h * 32 + dh];
    }
    __syncthreads();

    {
        int dh = t & 31, qq = t >> 5;
#pragma unroll
        for (int rep = 0; rep < 2; rep++) {
            int q = qq + 8 * rep;
            float acc = 0.f;
#pragma unroll 8
            for (int k2 = 0; k2 < 256; k2++) acc += sc[q][k2] * KV[k2][dh];
            ctx[(b * TT + q0 + q) * DD + h * 32 + dh] = f2bf(acc);
        }
    }
}

// ---------------- host launcher ----------------
extern "C" void kernel_launch(void* const* d_in, const int* in_sizes, int n_in,
                              void* d_out, int out_size, void* d_ws, size_t ws_size,
                              hipStream_t stream) {
    const int*   src      = (const int*)  d_in[0];
    const int*   lengths  = (const int*)  d_in[1];
    const float* bond     = (const float*)d_in[2];
    const float* timestep = (const float*)d_in[3];
    const float* emb      = (const float*)d_in[4];
    const float* t_w1     = (const float*)d_in[5];
    const float* t_b1     = (const float*)d_in[6];
    const float* t_w2     = (const float*)d_in[7];
    const float* t_b2     = (const float*)d_in[8];
    const float* u        = (const float*)d_in[9];
    const float* v        = (const float*)d_in[10];
    const float* Wq       = (const float*)d_in[11];
    const float* bq       = (const float*)d_in[12];
    const float* Wk       = (const float*)d_in[13];
    const float* bk       = (const float*)d_in[14];
    const float* Wv       = (const float*)d_in[15];
    const float* bv       = (const float*)d_in[16];
    const float* Wo       = (const float*)d_in[17];
    const float* bo       = (const float*)d_in[18];
    const float* ln1_g    = (const float*)d_in[19];
    const float* ln1_b    = (const float*)d_in[20];
    const float* ln2_g    = (const float*)d_in[21];
    const float* ln2_b    = (const float*)d_in[22];
    const float* ff_w1    = (const float*)d_in[23];
    const float* ff_b1    = (const float*)d_in[24];
    const float* ff_w2    = (const float*)d_in[25];
    const float* ff_b2    = (const float*)d_in[26];
    const float* lnf_g    = (const float*)d_in[27];
    const float* lnf_b    = (const float*)d_in[28];

    float* ws   = (float*)d_ws;
    float* xbuf = ws;                       // 524288 f32
    float* qbuf = xbuf + 524288;
    float* kbuf = qbuf + 524288;
    float* vbuf = kbuf + 524288;
    float* obuf = vbuf + 524288;
    float* temb = obuf + 524288;            // 1024
    ushort* hbuf_bf  = (ushort*)(temb + 1024);          // 524288 ushort
    ushort* cbuf_bf  = hbuf_bf + 524288;                // 524288
    ushort* ffbuf_bf = cbuf_bf + 524288;                // 2097152
    ushort* wq_bf    = ffbuf_bf + 2097152;              // 262144
    ushort* wk_bf    = wq_bf + 262144;
    ushort* wv_bf    = wk_bf + 262144;
    ushort* wo_bf    = wv_bf + 262144;
    ushort* ffw1_bf  = wo_bf + 262144;                  // 1048576
    ushort* ffw2_bf  = ffw1_bf + 1048576;               // 1048576

    // convert weights to bf16 (same work every call)
    convert_bf16_kernel<<<256, 256, 0, stream>>>(Wq, wq_bf, 65536);
    convert_bf16_kernel<<<256, 256, 0, stream>>>(Wk, wk_bf, 65536);
    convert_bf16_kernel<<<256, 256, 0, stream>>>(Wv, wv_bf, 65536);
    convert_bf16_kernel<<<256, 256, 0, stream>>>(Wo, wo_bf, 65536);
    convert_bf16_kernel<<<1024, 256, 0, stream>>>(ff_w1, ffw1_bf, 262144);
    convert_bf16_kernel<<<1024, 256, 0, stream>>>(ff_w2, ffw2_bf, 262144);

    temb_kernel<<<8, 128, 0, stream>>>(timestep, t_w1, t_b1, t_w2, t_b2, temb);
    embed_kernel<<<2048, 256, 0, stream>>>(src, emb, xbuf);

    const float scale = 0.17677669529663687f;  // 1/sqrt(32)
    dim3 gqkv(4, 64, 3);
    dim3 g256(4, 64);
    dim3 g1024(16, 64);

    for (int l = 0; l < LL; l++) {
        ln_kernel<1><<<2048, 256, 0, stream>>>(xbuf, ln1_g + l * 256, ln1_b + l * 256, hbuf_bf);
        qkv_bf16<<<gqkv, 128, 0, stream>>>(hbuf_bf,
            wq_bf + l * 65536, bq + l * 256, qbuf,
            wk_bf + l * 65536, bk + l * 256, kbuf,
            wv_bf + l * 65536, bv + l * 256, vbuf, scale);
        attn_kernel<<<dim3(16, 8, 8), 256, 0, stream>>>(qbuf, kbuf, vbuf, u, v, temb, bond, lengths, cbuf_bf);
        gemm_bf16<0, 0><<<g256, 128, 0, stream>>>(cbuf_bf, wo_bf + l * 65536, bo + l * 256, xbuf, obuf, 256, 256, 1.f);
        ln_kernel<1><<<2048, 256, 0, stream>>>(obuf, ln2_g + l * 256, ln2_b + l * 256, hbuf_bf);
        gemm_bf16<1, 1><<<g1024, 128, 0, stream>>>(hbuf_bf, ffw1_bf + l * 262144, ff_b1 + l * 1024, nullptr, ffbuf_bf, 1024, 256, 1.f);
        gemm_bf16<0, 0><<<g256, 128, 0, stream>>>(ffbuf_bf, ffw2_bf + l * 262144, ff_b2 + l * 256, obuf, xbuf, 256, 1024, 1.f);
    }
    ln_kernel<0><<<2048, 256, 0, stream>>>(xbuf, lnf_g, lnf_b, (float*)d_out);
}

// Round 11
// 606.224 us; speedup vs baseline: 1.2964x; 1.2964x over previous
//
#include <hip/hip_runtime.h>
#include <hip/hip_bf16.h>
#include <math.h>

#define BB 8
#define TT 256
#define DD 256
#define HH 8
#define DHH 32
#define LL 4
#define DFF 1024
#define QTILE 16

#define RBF_DELTA 0.05039370078740158f
#define RBF_INVGAP 20.0f

typedef __attribute__((ext_vector_type(8))) short short8v;
typedef __attribute__((ext_vector_type(4))) short short4v;
typedef __attribute__((ext_vector_type(4))) float f32x4;

__device__ __forceinline__ ushort f2bf(float x) {
    __hip_bfloat16 h = __float2bfloat16(x);
    return *reinterpret_cast<ushort*>(&h);
}

// ---------------- transpose + convert: W f32 [K][N] -> Wt bf16 [N][K] -------
// block (32,8), grid (N/32, K/32, L)
__global__ void transpose_bf16_kernel(const float* __restrict__ in, ushort* __restrict__ out,
                                      int K, int N, int lstride) {
    __shared__ float tile[32][33];
    int l = blockIdx.z;
    const float* W = in + (size_t)l * lstride;
    ushort* Wt = out + (size_t)l * lstride;
    int kb = blockIdx.y * 32, nb = blockIdx.x * 32;
    int tx = threadIdx.x, ty = threadIdx.y;
#pragma unroll
    for (int i = 0; i < 4; i++) {
        int r = ty + i * 8;
        tile[r][tx] = W[(kb + r) * N + nb + tx];
    }
    __syncthreads();
#pragma unroll
    for (int i = 0; i < 4; i++) {
        int r = ty + i * 8;
        Wt[(nb + r) * K + kb + tx] = f2bf(tile[tx][r]);   // FIXED: was out[...]
    }
}

// ---------------- temb ----------------
__global__ void temb_kernel(const float* __restrict__ timestep,
                            const float* __restrict__ t_w1, const float* __restrict__ t_b1,
                            const float* __restrict__ t_w2, const float* __restrict__ t_b2,
                            float* __restrict__ temb_out) {
    __shared__ float s0[128], s1[128];
    int b = blockIdx.x, j = threadIdx.x;
    float ts = timestep[b];
    const float LOG1E4 = 9.210340371976184f;
    if (j < 64) {
        float f = expf(-LOG1E4 * (float)j / 64.f);
        s0[j] = cosf(ts * f);
    } else {
        int i = j - 64;
        float f = expf(-LOG1E4 * (float)i / 64.f);
        s0[j] = sinf(ts * f);
    }
    __syncthreads();
    float acc = t_b1[j];
    for (int i = 0; i < 128; i++) acc += s0[i] * t_w1[i * 128 + j];
    acc = acc / (1.f + expf(-acc));
    s1[j] = acc;
    __syncthreads();
    float acc2 = t_b2[j];
    for (int i = 0; i < 128; i++) acc2 += s1[i] * t_w2[i * 128 + j];
    temb_out[b * 128 + j] = acc2;
}

// ---------------- embedding ----------------
__global__ void embed_kernel(const int* __restrict__ src, const float* __restrict__ emb,
                             float* __restrict__ x) {
    int r = blockIdx.x, d = threadIdx.x;
    x[r * DD + d] = emb[src[r] * DD + d];
}

// ---------------- LayerNorm ----------------
template <int OUT_BF16>
__global__ void ln_kernel(const float* __restrict__ in, const float* __restrict__ g,
                          const float* __restrict__ bta, void* __restrict__ out) {
    __shared__ float red[8];
    __shared__ float mv[2];
    int r = blockIdx.x, t = threadIdx.x;
    float v = in[r * DD + t];
    float s = v, s2 = v * v;
    for (int off = 32; off > 0; off >>= 1) {
        s += __shfl_xor(s, off);
        s2 += __shfl_xor(s2, off);
    }
    int w = t >> 6;
    if ((t & 63) == 0) { red[w] = s; red[4 + w] = s2; }
    __syncthreads();
    if (t == 0) {
        float S = red[0] + red[1] + red[2] + red[3];
        float S2 = red[4] + red[5] + red[6] + red[7];
        float m = S * (1.f / 256.f);
        float var = S2 * (1.f / 256.f) - m * m;
        mv[0] = m; mv[1] = rsqrtf(var + 1e-6f);
    }
    __syncthreads();
    float o = (v - mv[0]) * mv[1] * g[t] + bta[t];
    if (OUT_BF16) ((ushort*)out)[r * DD + t] = f2bf(o);
    else          ((float*)out)[r * DD + t] = o;
}

// ---------------- bf16 MFMA GEMM, 4-wave split-K ----------------
// C[M,N] = (A[M,K](bf16) @ W[K,N] + bias)*scale (+relu) (+resid f32)
// W given TRANSPOSED: Wt[N][K] bf16. tile M=16, N=64, BK=128; 256 thr = 4 waves,
// wave w owns k-slice [w*32,(w+1)*32) of each tile; LDS reduce at end.
// Swizzle: byte ^= (row&7)<<4 on write and read (rule #21 both-sides).
__device__ __forceinline__ void gemm_mfma_body(
    const ushort* __restrict__ A, const ushort* __restrict__ Wt,
    const float* __restrict__ bias, const float* __restrict__ resid,
    void* __restrict__ out, int N, int K, float scale, int RELU, int OUT_BF16) {
    __shared__ __align__(16) ushort smem[10240];   // As 16*128 | Bs 64*128 (20KB)
    ushort* As = smem;
    ushort* Bs = smem + 2048;
    float* red = (float*)smem;                     // 3*64*16 f32 = 12KB aliased

    int tid = threadIdx.x;
    int w = tid >> 6, lane = tid & 63;
    int m0 = blockIdx.y * 16, n0 = blockIdx.x * 64;

    f32x4 acc[4] = {f32x4{0,0,0,0}, f32x4{0,0,0,0}, f32x4{0,0,0,0}, f32x4{0,0,0,0}};

    for (int k0 = 0; k0 < K; k0 += 128) {
        {   // stage A 16 rows x 128 k: 1 iter, 16B/thread
            int r = tid >> 4, k8 = tid & 15;
            short8v av = *reinterpret_cast<const short8v*>(&A[(m0 + r) * K + k0 + k8 * 8]);
            int dstb = r * 256 + ((k8 * 16) ^ ((r & 7) << 4));
            *reinterpret_cast<short8v*>((char*)As + dstb) = av;
        }
#pragma unroll
        for (int it = 0; it < 4; it++) {   // stage B 64 rows x 128 k
            int idx = it * 256 + tid;
            int r = idx >> 4, k8 = idx & 15;
            short8v bv = *reinterpret_cast<const short8v*>(&Wt[(n0 + r) * K + k0 + k8 * 8]);
            int dstb = r * 256 + ((k8 * 16) ^ ((r & 7) << 4));
            *reinterpret_cast<short8v*>((char*)Bs + dstb) = bv;
        }
        __syncthreads();
        int kb = w * 64 + (lane >> 4) * 16;   // wave k-slice (bytes)
        int arow = lane & 15;
        short8v a = *reinterpret_cast<const short8v*>(
            (char*)As + arow * 256 + (kb ^ ((arow & 7) << 4)));
#pragma unroll
        for (int nb = 0; nb < 4; nb++) {
            int nrow = nb * 16 + (lane & 15);
            short8v b = *reinterpret_cast<const short8v*>(
                (char*)Bs + nrow * 256 + (kb ^ ((nrow & 7) << 4)));
            acc[nb] = __builtin_amdgcn_mfma_f32_16x16x32_bf16(a, b, acc[nb], 0, 0, 0);
        }
        __syncthreads();
    }
    // cross-wave reduction
    if (w > 0) {
        float* r0 = &red[((w - 1) * 64 + lane) * 16];
#pragma unroll
        for (int nb = 0; nb < 4; nb++)
            *reinterpret_cast<f32x4*>(&r0[nb * 4]) = acc[nb];
    }
    __syncthreads();
    if (w == 0) {
        const float* r0 = &red[lane * 16];
        const float* r1 = &red[(64 + lane) * 16];
        const float* r2 = &red[(128 + lane) * 16];
        int col = lane & 15;
#pragma unroll
        for (int nb = 0; nb < 4; nb++) {
            int n = n0 + nb * 16 + col;
            float bia = bias[n];
#pragma unroll
            for (int i = 0; i < 4; i++) {
                int idx = nb * 4 + i;
                int m = m0 + (lane >> 4) * 4 + i;
                float v = acc[nb][i] + r0[idx] + r1[idx] + r2[idx];
                v = (v + bia) * scale;
                if (RELU) v = fmaxf(v, 0.f);
                if (resid) v += resid[m * N + n];
                if (OUT_BF16) ((ushort*)out)[m * N + n] = f2bf(v);
                else          ((float*)out)[m * N + n] = v;
            }
        }
    }
}

template <int RELU, int OUT_BF16>
__global__ __launch_bounds__(256) void gemm_bf16(
    const ushort* __restrict__ A, const ushort* __restrict__ Wt,
    const float* __restrict__ bias, const float* __restrict__ resid,
    void* __restrict__ out, int N, int K, float scale) {
    gemm_mfma_body(A, Wt, bias, resid, out, N, K, scale, RELU, OUT_BF16);
}

__global__ __launch_bounds__(256) void qkv_bf16(
    const ushort* __restrict__ A,
    const ushort* __restrict__ Wqt, const float* __restrict__ bq, float* __restrict__ qo,
    const ushort* __restrict__ Wkt, const float* __restrict__ bk, float* __restrict__ ko,
    const ushort* __restrict__ Wvt, const float* __restrict__ bv, float* __restrict__ vo,
    float qscale) {
    int z = blockIdx.z;
    const ushort* W = (z == 0) ? Wqt : (z == 1) ? Wkt : Wvt;
    const float* bi = (z == 0) ? bq : (z == 1) ? bk : bv;
    float* o = (z == 0) ? qo : (z == 1) ? ko : vo;
    float sc = (z == 0) ? qscale : 1.f;
    gemm_mfma_body(A, W, bi, nullptr, o, DD, DD, sc, 0, 0);
}

// ---------------- fused attention (unchanged) ----------------
__global__ __launch_bounds__(256, 2) void attn_kernel(
    const float* __restrict__ qbuf, const float* __restrict__ kbuf,
    const float* __restrict__ vbuf, const float* __restrict__ u,
    const float* __restrict__ v, const float* __restrict__ temb,
    const float* __restrict__ bond, const int* __restrict__ lengths,
    ushort* __restrict__ ctx) {
    __shared__ float KV[256][33];
    __shared__ float sc[QTILE][257];
    __shared__ float qu_s[QTILE][32], qv_s[QTILE][32];
    __shared__ float tq[QTILE];
    __shared__ float temb_s[32];

    int qt = blockIdx.x;
    int h  = blockIdx.y;
    int b  = blockIdx.z;
    int t  = threadIdx.x;
    int len = lengths[b];
    int q0 = qt * QTILE;

    for (int e = t; e < QTILE * 32; e += 256) {
        int q = e >> 5, dh = e & 31;
        float qs = qbuf[(b * TT + q0 + q) * DD + h * 32 + dh];
        qu_s[q][dh] = qs + u[h * 32 + dh];
        qv_s[q][dh] = qs + v[h * 32 + dh];
    }
    if (t < 32) temb_s[t] = (h >= 4) ? temb[b * 128 + (h - 4) * 32 + t] : 0.f;
    for (int e = t; e < 256 * 32; e += 256) {
        int k = e >> 5, dh = e & 31;
        KV[k][dh] = kbuf[(b * TT + k) * DD + h * 32 + dh];
    }
    __syncthreads();

    if (t < QTILE) {
        float a = 0.f;
#pragma unroll
        for (int j = 0; j < 32; j++) a += qv_s[t][j] * temb_s[j];
        tq[t] = a;
    }
    __syncthreads();

    {
        int k = t;
        bool kvalid = k < len;
        float c0 = (float)(h * 32) * RBF_DELTA;
        for (int q = 0; q < QTILE; q++) {
            float s;
            if (!kvalid) {
                s = -1e18f;
            } else {
                float accA = 0.f;
#pragma unroll
                for (int dh = 0; dh < 32; dh++) accA += qu_s[q][dh] * KV[k][dh];
                float accB;
                if (h < 4) {
                    accB = 0.f;
                    if (q0 + q < len) {
                        float d = bond[(b * TT + q0 + q) * TT + k];
#pragma unroll
                        for (int j = 0; j < 32; j++) {
                            float diff = d - (c0 + j * RBF_DELTA);
                            accB += qv_s[q][j] * __expf(-diff * diff * RBF_INVGAP);
                        }
                    }
                } else {
                    accB = tq[q];
                }
                s = accA + accB;
            }
            sc[q][k] = s;
        }
    }
    __syncthreads();

    {
        int r = t >> 4, j = t & 15;
        float vals[16];
        float mx = -1e30f;
#pragma unroll
        for (int i = 0; i < 16; i++) {
            vals[i] = sc[r][j + 16 * i];
            mx = fmaxf(mx, vals[i]);
        }
        for (int off = 8; off > 0; off >>= 1) mx = fmaxf(mx, __shfl_xor(mx, off));
        float sum = 0.f;
#pragma unroll
        for (int i = 0; i < 16; i++) {
            float e = __expf(vals[i] - mx);
            vals[i] = e; sum += e;
        }
        for (int off = 8; off > 0; off >>= 1) sum += __shfl_xor(sum, off);
        float inv = 1.f / sum;
#pragma unroll
        for (int i = 0; i < 16; i++) sc[r][j + 16 * i] = vals[i] * inv;
    }
    for (int e = t; e < 256 * 32; e += 256) {
        int k2 = e >> 5, dh = e & 31;
        KV[k2][dh] = vbuf[(b * TT + k2) * DD + h * 32 + dh];
    }
    __syncthreads();

    {
        int dh = t & 31, qq = t >> 5;
#pragma unroll
        for (int rep = 0; rep < 2; rep++) {
            int q = qq + 8 * rep;
            float acc = 0.f;
#pragma unroll 8
            for (int k2 = 0; k2 < 256; k2++) acc += sc[q][k2] * KV[k2][dh];
            ctx[(b * TT + q0 + q) * DD + h * 32 + dh] = f2bf(acc);
        }
    }
}

// ---------------- host launcher ----------------
extern "C" void kernel_launch(void* const* d_in, const int* in_sizes, int n_in,
                              void* d_out, int out_size, void* d_ws, size_t ws_size,
                              hipStream_t stream) {
    const int*   src      = (const int*)  d_in[0];
    const int*   lengths  = (const int*)  d_in[1];
    const float* bond     = (const float*)d_in[2];
    const float* timestep = (const float*)d_in[3];
    const float* emb      = (const float*)d_in[4];
    const float* t_w1     = (const float*)d_in[5];
    const float* t_b1     = (const float*)d_in[6];
    const float* t_w2     = (const float*)d_in[7];
    const float* t_b2     = (const float*)d_in[8];
    const float* u        = (const float*)d_in[9];
    const float* v        = (const float*)d_in[10];
    const float* Wq       = (const float*)d_in[11];
    const float* bq       = (const float*)d_in[12];
    const float* Wk       = (const float*)d_in[13];
    const float* bk       = (const float*)d_in[14];
    const float* Wv       = (const float*)d_in[15];
    const float* bv       = (const float*)d_in[16];
    const float* Wo       = (const float*)d_in[17];
    const float* bo       = (const float*)d_in[18];
    const float* ln1_g    = (const float*)d_in[19];
    const float* ln1_b    = (const float*)d_in[20];
    const float* ln2_g    = (const float*)d_in[21];
    const float* ln2_b    = (const float*)d_in[22];
    const float* ff_w1    = (const float*)d_in[23];
    const float* ff_b1    = (const float*)d_in[24];
    const float* ff_w2    = (const float*)d_in[25];
    const float* ff_b2    = (const float*)d_in[26];
    const float* lnf_g    = (const float*)d_in[27];
    const float* lnf_b    = (const float*)d_in[28];

    float* ws   = (float*)d_ws;
    float* xbuf = ws;                       // 524288 f32
    float* qbuf = xbuf + 524288;
    float* kbuf = qbuf + 524288;
    float* vbuf = kbuf + 524288;
    float* obuf = vbuf + 524288;
    float* temb = obuf + 524288;            // 1024
    ushort* hbuf_bf  = (ushort*)(temb + 1024);
    ushort* cbuf_bf  = hbuf_bf + 524288;
    ushort* ffbuf_bf = cbuf_bf + 524288;                // 2097152
    ushort* wqt_bf   = ffbuf_bf + 2097152;              // 262144 each
    ushort* wkt_bf   = wqt_bf + 262144;
    ushort* wvt_bf   = wkt_bf + 262144;
    ushort* wot_bf   = wvt_bf + 262144;
    ushort* ffw1t_bf = wot_bf + 262144;                 // 1048576
    ushort* ffw2t_bf = ffw1t_bf + 1048576;              // 1048576

    // transpose+convert weights (same work every call)
    dim3 tb(32, 8);
    transpose_bf16_kernel<<<dim3(8, 8, 4), tb, 0, stream>>>(Wq, wqt_bf, 256, 256, 65536);
    transpose_bf16_kernel<<<dim3(8, 8, 4), tb, 0, stream>>>(Wk, wkt_bf, 256, 256, 65536);
    transpose_bf16_kernel<<<dim3(8, 8, 4), tb, 0, stream>>>(Wv, wvt_bf, 256, 256, 65536);
    transpose_bf16_kernel<<<dim3(8, 8, 4), tb, 0, stream>>>(Wo, wot_bf, 256, 256, 65536);
    transpose_bf16_kernel<<<dim3(32, 8, 4), tb, 0, stream>>>(ff_w1, ffw1t_bf, 256, 1024, 262144);
    transpose_bf16_kernel<<<dim3(8, 32, 4), tb, 0, stream>>>(ff_w2, ffw2t_bf, 1024, 256, 262144);

    temb_kernel<<<8, 128, 0, stream>>>(timestep, t_w1, t_b1, t_w2, t_b2, temb);
    embed_kernel<<<2048, 256, 0, stream>>>(src, emb, xbuf);

    const float scale = 0.17677669529663687f;  // 1/sqrt(32)
    dim3 gqkv(4, 128, 3);
    dim3 g256(4, 128);
    dim3 g1024(16, 128);

    for (int l = 0; l < LL; l++) {
        ln_kernel<1><<<2048, 256, 0, stream>>>(xbuf, ln1_g + l * 256, ln1_b + l * 256, hbuf_bf);
        qkv_bf16<<<gqkv, 256, 0, stream>>>(hbuf_bf,
            wqt_bf + l * 65536, bq + l * 256, qbuf,
            wkt_bf + l * 65536, bk + l * 256, kbuf,
            wvt_bf + l * 65536, bv + l * 256, vbuf, scale);
        attn_kernel<<<dim3(16, 8, 8), 256, 0, stream>>>(qbuf, kbuf, vbuf, u, v, temb, bond, lengths, cbuf_bf);
        gemm_bf16<0, 0><<<g256, 256, 0, stream>>>(cbuf_bf, wot_bf + l * 65536, bo + l * 256, xbuf, obuf, 256, 256, 1.f);
        ln_kernel<1><<<2048, 256, 0, stream>>>(obuf, ln2_g + l * 256, ln2_b + l * 256, hbuf_bf);
        gemm_bf16<1, 1><<<g1024, 256, 0, stream>>>(hbuf_bf, ffw1t_bf + l * 262144, ff_b1 + l * 1024, nullptr, ffbuf_bf, 1024, 256, 1.f);
        gemm_bf16<0, 0><<<g256, 256, 0, stream>>>(ffbuf_bf, ffw2t_bf + l * 262144, ff_b2 + l * 256, obuf, xbuf, 256, 1024, 1.f);
    }
    ln_kernel<0><<<2048, 256, 0, stream>>>(xbuf, lnf_g, lnf_b, (float*)d_out);
}

// Round 12
// 580.390 us; speedup vs baseline: 1.3541x; 1.0445x over previous
//
#include <hip/hip_runtime.h>
#include <hip/hip_bf16.h>
#include <math.h>

#define BB 8
#define TT 256
#define DD 256
#define HH 8
#define DHH 32
#define LL 4
#define DFF 1024
#define QTILE 16

#define RBF_DELTA 0.05039370078740158f
#define RBF_NEGK -28.853900817779268f   // -20/ln(2): exp(-20*diff^2) = exp2(NEGK*diff^2)

typedef __attribute__((ext_vector_type(8))) short short8v;
typedef __attribute__((ext_vector_type(4))) short short4v;
typedef __attribute__((ext_vector_type(4))) float f32x4;

__device__ __forceinline__ ushort f2bf(float x) {
    __hip_bfloat16 h = __float2bfloat16(x);
    return *reinterpret_cast<ushort*>(&h);
}

// ---------------- transpose + convert: W f32 [K][N] -> Wt bf16 [N][K] -------
__global__ void transpose_bf16_kernel(const float* __restrict__ in, ushort* __restrict__ out,
                                      int K, int N, int lstride) {
    __shared__ float tile[32][33];
    int l = blockIdx.z;
    const float* W = in + (size_t)l * lstride;
    ushort* Wt = out + (size_t)l * lstride;
    int kb = blockIdx.y * 32, nb = blockIdx.x * 32;
    int tx = threadIdx.x, ty = threadIdx.y;
#pragma unroll
    for (int i = 0; i < 4; i++) {
        int r = ty + i * 8;
        tile[r][tx] = W[(kb + r) * N + nb + tx];
    }
    __syncthreads();
#pragma unroll
    for (int i = 0; i < 4; i++) {
        int r = ty + i * 8;
        Wt[(nb + r) * K + kb + tx] = f2bf(tile[tx][r]);
    }
}

// ---------------- temb ----------------
__global__ void temb_kernel(const float* __restrict__ timestep,
                            const float* __restrict__ t_w1, const float* __restrict__ t_b1,
                            const float* __restrict__ t_w2, const float* __restrict__ t_b2,
                            float* __restrict__ temb_out) {
    __shared__ float s0[128], s1[128];
    int b = blockIdx.x, j = threadIdx.x;
    float ts = timestep[b];
    const float LOG1E4 = 9.210340371976184f;
    if (j < 64) {
        float f = expf(-LOG1E4 * (float)j / 64.f);
        s0[j] = cosf(ts * f);
    } else {
        int i = j - 64;
        float f = expf(-LOG1E4 * (float)i / 64.f);
        s0[j] = sinf(ts * f);
    }
    __syncthreads();
    float acc = t_b1[j];
    for (int i = 0; i < 128; i++) acc += s0[i] * t_w1[i * 128 + j];
    acc = acc / (1.f + expf(-acc));
    s1[j] = acc;
    __syncthreads();
    float acc2 = t_b2[j];
    for (int i = 0; i < 128; i++) acc2 += s1[i] * t_w2[i * 128 + j];
    temb_out[b * 128 + j] = acc2;
}

// ---------------- embedding ----------------
__global__ void embed_kernel(const int* __restrict__ src, const float* __restrict__ emb,
                             float* __restrict__ x) {
    int r = blockIdx.x, d = threadIdx.x;
    x[r * DD + d] = emb[src[r] * DD + d];
}

// ---------------- LayerNorm ----------------
template <int OUT_BF16>
__global__ void ln_kernel(const float* __restrict__ in, const float* __restrict__ g,
                          const float* __restrict__ bta, void* __restrict__ out) {
    __shared__ float red[8];
    __shared__ float mv[2];
    int r = blockIdx.x, t = threadIdx.x;
    float v = in[r * DD + t];
    float s = v, s2 = v * v;
    for (int off = 32; off > 0; off >>= 1) {
        s += __shfl_xor(s, off);
        s2 += __shfl_xor(s2, off);
    }
    int w = t >> 6;
    if ((t & 63) == 0) { red[w] = s; red[4 + w] = s2; }
    __syncthreads();
    if (t == 0) {
        float S = red[0] + red[1] + red[2] + red[3];
        float S2 = red[4] + red[5] + red[6] + red[7];
        float m = S * (1.f / 256.f);
        float var = S2 * (1.f / 256.f) - m * m;
        mv[0] = m; mv[1] = rsqrtf(var + 1e-6f);
    }
    __syncthreads();
    float o = (v - mv[0]) * mv[1] * g[t] + bta[t];
    if (OUT_BF16) ((ushort*)out)[r * DD + t] = f2bf(o);
    else          ((float*)out)[r * DD + t] = o;
}

// ---------------- bf16 MFMA GEMM, 4-wave split-K (unchanged, verified) ------
__device__ __forceinline__ void gemm_mfma_body(
    const ushort* __restrict__ A, const ushort* __restrict__ Wt,
    const float* __restrict__ bias, const float* __restrict__ resid,
    void* __restrict__ out, int N, int K, float scale, int RELU, int OUT_BF16) {
    __shared__ __align__(16) ushort smem[10240];
    ushort* As = smem;
    ushort* Bs = smem + 2048;
    float* red = (float*)smem;

    int tid = threadIdx.x;
    int w = tid >> 6, lane = tid & 63;
    int m0 = blockIdx.y * 16, n0 = blockIdx.x * 64;

    f32x4 acc[4] = {f32x4{0,0,0,0}, f32x4{0,0,0,0}, f32x4{0,0,0,0}, f32x4{0,0,0,0}};

    for (int k0 = 0; k0 < K; k0 += 128) {
        {
            int r = tid >> 4, k8 = tid & 15;
            short8v av = *reinterpret_cast<const short8v*>(&A[(m0 + r) * K + k0 + k8 * 8]);
            int dstb = r * 256 + ((k8 * 16) ^ ((r & 7) << 4));
            *reinterpret_cast<short8v*>((char*)As + dstb) = av;
        }
#pragma unroll
        for (int it = 0; it < 4; it++) {
            int idx = it * 256 + tid;
            int r = idx >> 4, k8 = idx & 15;
            short8v bv = *reinterpret_cast<const short8v*>(&Wt[(n0 + r) * K + k0 + k8 * 8]);
            int dstb = r * 256 + ((k8 * 16) ^ ((r & 7) << 4));
            *reinterpret_cast<short8v*>((char*)Bs + dstb) = bv;
        }
        __syncthreads();
        int kb = w * 64 + (lane >> 4) * 16;
        int arow = lane & 15;
        short8v a = *reinterpret_cast<const short8v*>(
            (char*)As + arow * 256 + (kb ^ ((arow & 7) << 4)));
#pragma unroll
        for (int nb = 0; nb < 4; nb++) {
            int nrow = nb * 16 + (lane & 15);
            short8v b = *reinterpret_cast<const short8v*>(
                (char*)Bs + nrow * 256 + (kb ^ ((nrow & 7) << 4)));
            acc[nb] = __builtin_amdgcn_mfma_f32_16x16x32_bf16(a, b, acc[nb], 0, 0, 0);
        }
        __syncthreads();
    }
    if (w > 0) {
        float* r0 = &red[((w - 1) * 64 + lane) * 16];
#pragma unroll
        for (int nb = 0; nb < 4; nb++)
            *reinterpret_cast<f32x4*>(&r0[nb * 4]) = acc[nb];
    }
    __syncthreads();
    if (w == 0) {
        const float* r0 = &red[lane * 16];
        const float* r1 = &red[(64 + lane) * 16];
        const float* r2 = &red[(128 + lane) * 16];
        int col = lane & 15;
#pragma unroll
        for (int nb = 0; nb < 4; nb++) {
            int n = n0 + nb * 16 + col;
            float bia = bias[n];
#pragma unroll
            for (int i = 0; i < 4; i++) {
                int idx = nb * 4 + i;
                int m = m0 + (lane >> 4) * 4 + i;
                float v = acc[nb][i] + r0[idx] + r1[idx] + r2[idx];
                v = (v + bia) * scale;
                if (RELU) v = fmaxf(v, 0.f);
                if (resid) v += resid[m * N + n];
                if (OUT_BF16) ((ushort*)out)[m * N + n] = f2bf(v);
                else          ((float*)out)[m * N + n] = v;
            }
        }
    }
}

template <int RELU, int OUT_BF16>
__global__ __launch_bounds__(256) void gemm_bf16(
    const ushort* __restrict__ A, const ushort* __restrict__ Wt,
    const float* __restrict__ bias, const float* __restrict__ resid,
    void* __restrict__ out, int N, int K, float scale) {
    gemm_mfma_body(A, Wt, bias, resid, out, N, K, scale, RELU, OUT_BF16);
}

__global__ __launch_bounds__(256) void qkv_bf16(
    const ushort* __restrict__ A,
    const ushort* __restrict__ Wqt, const float* __restrict__ bq, float* __restrict__ qo,
    const ushort* __restrict__ Wkt, const float* __restrict__ bk, float* __restrict__ ko,
    const ushort* __restrict__ Wvt, const float* __restrict__ bv, float* __restrict__ vo,
    float qscale) {
    int z = blockIdx.z;
    const ushort* W = (z == 0) ? Wqt : (z == 1) ? Wkt : Wvt;
    const float* bi = (z == 0) ? bq : (z == 1) ? bk : bv;
    float* o = (z == 0) ? qo : (z == 1) ? ko : vo;
    float sc = (z == 0) ? qscale : 1.f;
    gemm_mfma_body(A, W, bi, nullptr, o, DD, DD, sc, 0, 0);
}

// ---------------- fused attention v3 ----------------
// LDS 53696B -> 3 blocks/CU (was 54784 -> 2). KV XOR-swizzled (no pad),
// K row cached in 32 regs, float4 LDS reads, exp2-form RBF.
__global__ __launch_bounds__(256, 3) void attn_kernel(
    const float* __restrict__ qbuf, const float* __restrict__ kbuf,
    const float* __restrict__ vbuf, const float* __restrict__ u,
    const float* __restrict__ v, const float* __restrict__ temb,
    const float* __restrict__ bond, const int* __restrict__ lengths,
    ushort* __restrict__ ctx) {
    __shared__ float KV[256 * 32];          // XOR swizzle: [k*32 + (dh ^ (k&31))]
    __shared__ float sc[QTILE][260];        // 260: 16B-aligned rows, mild-conflict pad
    __shared__ float qu_s[QTILE][32], qv_s[QTILE][32];
    __shared__ float tq[QTILE];
    __shared__ float temb_s[32];

    int qt = blockIdx.x;
    int h  = blockIdx.y;
    int b  = blockIdx.z;
    int t  = threadIdx.x;
    int len = lengths[b];
    int q0 = qt * QTILE;

    for (int e = t; e < QTILE * 32; e += 256) {
        int q = e >> 5, dh = e & 31;
        float qs = qbuf[(b * TT + q0 + q) * DD + h * 32 + dh];
        qu_s[q][dh] = qs + u[h * 32 + dh];
        qv_s[q][dh] = qs + v[h * 32 + dh];
    }
    if (t < 32) temb_s[t] = (h >= 4) ? temb[b * 128 + (h - 4) * 32 + t] : 0.f;
    // stage K (swizzled)
    for (int e = t; e < 256 * 32; e += 256) {
        int k = e >> 5, dh = e & 31;
        KV[k * 32 + (dh ^ (k & 31))] = kbuf[(b * TT + k) * DD + h * 32 + dh];
    }
    __syncthreads();

    if (t < QTILE) {
        float a = 0.f;
#pragma unroll
        for (int j = 0; j < 32; j++) a += qv_s[t][j] * temb_s[j];
        tq[t] = a;
    }
    __syncthreads();

    // cache this thread's K row (k = t) into registers
    float kreg[32];
    {
        int kx = t & 31;
#pragma unroll
        for (int dh = 0; dh < 32; dh++) kreg[dh] = KV[t * 32 + (dh ^ kx)];
    }

    // ---- scores: thread t owns key k = t, loops q ----
    {
        int k = t;
        bool kvalid = k < len;
        float c0 = (float)(h * 32) * RBF_DELTA;
        for (int q = 0; q < QTILE; q++) {
            float s;
            if (!kvalid) {
                s = -1e18f;
            } else {
                const float* qur = qu_s[q];
                float accA = 0.f;
#pragma unroll
                for (int c = 0; c < 8; c++) {
                    float4 q4 = *reinterpret_cast<const float4*>(&qur[c * 4]);
                    accA = fmaf(q4.x, kreg[c * 4 + 0], accA);
                    accA = fmaf(q4.y, kreg[c * 4 + 1], accA);
                    accA = fmaf(q4.z, kreg[c * 4 + 2], accA);
                    accA = fmaf(q4.w, kreg[c * 4 + 3], accA);
                }
                float accB;
                if (h < 4) {
                    accB = 0.f;
                    if (q0 + q < len) {
                        float d = bond[(size_t)(b * TT + q0 + q) * TT + k];
                        float diff = d - c0;
                        const float* qvr = qv_s[q];
#pragma unroll
                        for (int c = 0; c < 8; c++) {
                            float4 q4 = *reinterpret_cast<const float4*>(&qvr[c * 4]);
                            float p;
                            p = exp2f(diff * diff * RBF_NEGK);
                            accB = fmaf(q4.x, p, accB); diff -= RBF_DELTA;
                            p = exp2f(diff * diff * RBF_NEGK);
                            accB = fmaf(q4.y, p, accB); diff -= RBF_DELTA;
                            p = exp2f(diff * diff * RBF_NEGK);
                            accB = fmaf(q4.z, p, accB); diff -= RBF_DELTA;
                            p = exp2f(diff * diff * RBF_NEGK);
                            accB = fmaf(q4.w, p, accB); diff -= RBF_DELTA;
                        }
                    }
                } else {
                    accB = tq[q];
                }
                s = accA + accB;
            }
            sc[q][t] = s;
        }
    }
    __syncthreads();

    // ---- softmax: 16 threads per row ----
    {
        int r = t >> 4, j = t & 15;
        float vals[16];
        float mx = -1e30f;
#pragma unroll
        for (int i = 0; i < 16; i++) {
            vals[i] = sc[r][j + 16 * i];
            mx = fmaxf(mx, vals[i]);
        }
        for (int off = 8; off > 0; off >>= 1) mx = fmaxf(mx, __shfl_xor(mx, off));
        float sum = 0.f;
#pragma unroll
        for (int i = 0; i < 16; i++) {
            float e = __expf(vals[i] - mx);
            vals[i] = e; sum += e;
        }
        for (int off = 8; off > 0; off >>= 1) sum += __shfl_xor(sum, off);
        float inv = 1.f / sum;
#pragma unroll
        for (int i = 0; i < 16; i++) sc[r][j + 16 * i] = vals[i] * inv;
    }
    // restage V over K (swizzled; no KV reader between barriers)
    for (int e = t; e < 256 * 32; e += 256) {
        int k2 = e >> 5, dh = e & 31;
        KV[k2 * 32 + (dh ^ (k2 & 31))] = vbuf[(b * TT + k2) * DD + h * 32 + dh];
    }
    __syncthreads();

    // ---- ctx = attn @ V ----
    {
        int dh = t & 31, qq = t >> 5;
#pragma unroll
        for (int rep = 0; rep < 2; rep++) {
            int q = qq + 8 * rep;
            float acc = 0.f;
#pragma unroll 8
            for (int kk = 0; kk < 256; kk += 4) {
                float4 s4 = *reinterpret_cast<const float4*>(&sc[q][kk]);
                acc = fmaf(s4.x, KV[(kk + 0) * 32 + (dh ^ ((kk + 0) & 31))], acc);
                acc = fmaf(s4.y, KV[(kk + 1) * 32 + (dh ^ ((kk + 1) & 31))], acc);
                acc = fmaf(s4.z, KV[(kk + 2) * 32 + (dh ^ ((kk + 2) & 31))], acc);
                acc = fmaf(s4.w, KV[(kk + 3) * 32 + (dh ^ ((kk + 3) & 31))], acc);
            }
            ctx[(b * TT + q0 + q) * DD + h * 32 + dh] = f2bf(acc);
        }
    }
}

// ---------------- host launcher ----------------
extern "C" void kernel_launch(void* const* d_in, const int* in_sizes, int n_in,
                              void* d_out, int out_size, void* d_ws, size_t ws_size,
                              hipStream_t stream) {
    const int*   src      = (const int*)  d_in[0];
    const int*   lengths  = (const int*)  d_in[1];
    const float* bond     = (const float*)d_in[2];
    const float* timestep = (const float*)d_in[3];
    const float* emb      = (const float*)d_in[4];
    const float* t_w1     = (const float*)d_in[5];
    const float* t_b1     = (const float*)d_in[6];
    const float* t_w2     = (const float*)d_in[7];
    const float* t_b2     = (const float*)d_in[8];
    const float* u        = (const float*)d_in[9];
    const float* v        = (const float*)d_in[10];
    const float* Wq       = (const float*)d_in[11];
    const float* bq       = (const float*)d_in[12];
    const float* Wk       = (const float*)d_in[13];
    const float* bk       = (const float*)d_in[14];
    const float* Wv       = (const float*)d_in[15];
    const float* bv       = (const float*)d_in[16];
    const float* Wo       = (const float*)d_in[17];
    const float* bo       = (const float*)d_in[18];
    const float* ln1_g    = (const float*)d_in[19];
    const float* ln1_b    = (const float*)d_in[20];
    const float* ln2_g    = (const float*)d_in[21];
    const float* ln2_b    = (const float*)d_in[22];
    const float* ff_w1    = (const float*)d_in[23];
    const float* ff_b1    = (const float*)d_in[24];
    const float* ff_w2    = (const float*)d_in[25];
    const float* ff_b2    = (const float*)d_in[26];
    const float* lnf_g    = (const float*)d_in[27];
    const float* lnf_b    = (const float*)d_in[28];

    float* ws   = (float*)d_ws;
    float* xbuf = ws;
    float* qbuf = xbuf + 524288;
    float* kbuf = qbuf + 524288;
    float* vbuf = kbuf + 524288;
    float* obuf = vbuf + 524288;
    float* temb = obuf + 524288;
    ushort* hbuf_bf  = (ushort*)(temb + 1024);
    ushort* cbuf_bf  = hbuf_bf + 524288;
    ushort* ffbuf_bf = cbuf_bf + 524288;
    ushort* wqt_bf   = ffbuf_bf + 2097152;
    ushort* wkt_bf   = wqt_bf + 262144;
    ushort* wvt_bf   = wkt_bf + 262144;
    ushort* wot_bf   = wvt_bf + 262144;
    ushort* ffw1t_bf = wot_bf + 262144;
    ushort* ffw2t_bf = ffw1t_bf + 1048576;

    dim3 tb(32, 8);
    transpose_bf16_kernel<<<dim3(8, 8, 4), tb, 0, stream>>>(Wq, wqt_bf, 256, 256, 65536);
    transpose_bf16_kernel<<<dim3(8, 8, 4), tb, 0, stream>>>(Wk, wkt_bf, 256, 256, 65536);
    transpose_bf16_kernel<<<dim3(8, 8, 4), tb, 0, stream>>>(Wv, wvt_bf, 256, 256, 65536);
    transpose_bf16_kernel<<<dim3(8, 8, 4), tb, 0, stream>>>(Wo, wot_bf, 256, 256, 65536);
    transpose_bf16_kernel<<<dim3(32, 8, 4), tb, 0, stream>>>(ff_w1, ffw1t_bf, 256, 1024, 262144);
    transpose_bf16_kernel<<<dim3(8, 32, 4), tb, 0, stream>>>(ff_w2, ffw2t_bf, 1024, 256, 262144);

    temb_kernel<<<8, 128, 0, stream>>>(timestep, t_w1, t_b1, t_w2, t_b2, temb);
    embed_kernel<<<2048, 256, 0, stream>>>(src, emb, xbuf);

    const float scale = 0.17677669529663687f;  // 1/sqrt(32)
    dim3 gqkv(4, 128, 3);
    dim3 g256(4, 128);
    dim3 g1024(16, 128);

    for (int l = 0; l < LL; l++) {
        ln_kernel<1><<<2048, 256, 0, stream>>>(xbuf, ln1_g + l * 256, ln1_b + l * 256, hbuf_bf);
        qkv_bf16<<<gqkv, 256, 0, stream>>>(hbuf_bf,
            wqt_bf + l * 65536, bq + l * 256, qbuf,
            wkt_bf + l * 65536, bk + l * 256, kbuf,
            wvt_bf + l * 65536, bv + l * 256, vbuf, scale);
        attn_kernel<<<dim3(16, 8, 8), 256, 0, stream>>>(qbuf, kbuf, vbuf, u, v, temb, bond, lengths, cbuf_bf);
        gemm_bf16<0, 0><<<g256, 256, 0, stream>>>(cbuf_bf, wot_bf + l * 65536, bo + l * 256, xbuf, obuf, 256, 256, 1.f);
        ln_kernel<1><<<2048, 256, 0, stream>>>(obuf, ln2_g + l * 256, ln2_b + l * 256, hbuf_bf);
        gemm_bf16<1, 1><<<g1024, 256, 0, stream>>>(hbuf_bf, ffw1t_bf + l * 262144, ff_b1 + l * 1024, nullptr, ffbuf_bf, 1024, 256, 1.f);
        gemm_bf16<0, 0><<<g256, 256, 0, stream>>>(ffbuf_bf, ffw2t_bf + l * 262144, ff_b2 + l * 256, obuf, xbuf, 256, 1024, 1.f);
    }
    ln_kernel<0><<<2048, 256, 0, stream>>>(xbuf, lnf_g, lnf_b, (float*)d_out);
}

// Round 13
// 530.434 us; speedup vs baseline: 1.4816x; 1.0942x over previous
//
#include <hip/hip_runtime.h>
#include <hip/hip_bf16.h>
#include <math.h>

#define BB 8
#define TT 256
#define DD 256
#define HH 8
#define DHH 32
#define LL 4
#define DFF 1024
#define QTILE 16

#define RBF_DELTA 0.05039370078740158f
#define RBF_NEGK -28.853900817779268f     // -20/ln2
// factorized RBF: t_{j+1} = t_j * m_j ; m_0 = exp2(M0A*diff0 + M0B); m_{j+1} = m_j * RHO
#define RBF_M0A 2.9081851339f             // 2*(20/ln2)*DELTA
#define RBF_M0B -0.0732754690f            // -(20/ln2)*DELTA^2
#define RBF_RHO 0.9034077526f             // exp(-40*DELTA^2)

typedef __attribute__((ext_vector_type(8))) short short8v;
typedef __attribute__((ext_vector_type(4))) short short4v;
typedef __attribute__((ext_vector_type(4))) float f32x4;

__device__ __forceinline__ ushort f2bf(float x) {
    __hip_bfloat16 h = __float2bfloat16(x);
    return *reinterpret_cast<ushort*>(&h);
}

// ---------------- transpose + convert: W f32 [K][N] -> Wt bf16 [N][K] -------
__global__ void transpose_bf16_kernel(const float* __restrict__ in, ushort* __restrict__ out,
                                      int K, int N, int lstride) {
    __shared__ float tile[32][33];
    int l = blockIdx.z;
    const float* W = in + (size_t)l * lstride;
    ushort* Wt = out + (size_t)l * lstride;
    int kb = blockIdx.y * 32, nb = blockIdx.x * 32;
    int tx = threadIdx.x, ty = threadIdx.y;
#pragma unroll
    for (int i = 0; i < 4; i++) {
        int r = ty + i * 8;
        tile[r][tx] = W[(kb + r) * N + nb + tx];
    }
    __syncthreads();
#pragma unroll
    for (int i = 0; i < 4; i++) {
        int r = ty + i * 8;
        Wt[(nb + r) * K + kb + tx] = f2bf(tile[tx][r]);
    }
}

// ---------------- temb ----------------
__global__ void temb_kernel(const float* __restrict__ timestep,
                            const float* __restrict__ t_w1, const float* __restrict__ t_b1,
                            const float* __restrict__ t_w2, const float* __restrict__ t_b2,
                            float* __restrict__ temb_out) {
    __shared__ float s0[128], s1[128];
    int b = blockIdx.x, j = threadIdx.x;
    float ts = timestep[b];
    const float LOG1E4 = 9.210340371976184f;
    if (j < 64) {
        float f = expf(-LOG1E4 * (float)j / 64.f);
        s0[j] = cosf(ts * f);
    } else {
        int i = j - 64;
        float f = expf(-LOG1E4 * (float)i / 64.f);
        s0[j] = sinf(ts * f);
    }
    __syncthreads();
    float acc = t_b1[j];
    for (int i = 0; i < 128; i++) acc += s0[i] * t_w1[i * 128 + j];
    acc = acc / (1.f + expf(-acc));
    s1[j] = acc;
    __syncthreads();
    float acc2 = t_b2[j];
    for (int i = 0; i < 128; i++) acc2 += s1[i] * t_w2[i * 128 + j];
    temb_out[b * 128 + j] = acc2;
}

// ---------------- embedding ----------------
__global__ void embed_kernel(const int* __restrict__ src, const float* __restrict__ emb,
                             float* __restrict__ x) {
    int r = blockIdx.x, d = threadIdx.x;
    x[r * DD + d] = emb[src[r] * DD + d];
}

// ---------------- LayerNorm ----------------
template <int OUT_BF16>
__global__ void ln_kernel(const float* __restrict__ in, const float* __restrict__ g,
                          const float* __restrict__ bta, void* __restrict__ out) {
    __shared__ float red[8];
    __shared__ float mv[2];
    int r = blockIdx.x, t = threadIdx.x;
    float v = in[r * DD + t];
    float s = v, s2 = v * v;
    for (int off = 32; off > 0; off >>= 1) {
        s += __shfl_xor(s, off);
        s2 += __shfl_xor(s2, off);
    }
    int w = t >> 6;
    if ((t & 63) == 0) { red[w] = s; red[4 + w] = s2; }
    __syncthreads();
    if (t == 0) {
        float S = red[0] + red[1] + red[2] + red[3];
        float S2 = red[4] + red[5] + red[6] + red[7];
        float m = S * (1.f / 256.f);
        float var = S2 * (1.f / 256.f) - m * m;
        mv[0] = m; mv[1] = rsqrtf(var + 1e-6f);
    }
    __syncthreads();
    float o = (v - mv[0]) * mv[1] * g[t] + bta[t];
    if (OUT_BF16) ((ushort*)out)[r * DD + t] = f2bf(o);
    else          ((float*)out)[r * DD + t] = o;
}

// ---------------- bf16 MFMA GEMM, 4-wave split-K (unchanged, verified) ------
__device__ __forceinline__ void gemm_mfma_body(
    const ushort* __restrict__ A, const ushort* __restrict__ Wt,
    const float* __restrict__ bias, const float* __restrict__ resid,
    void* __restrict__ out, int N, int K, float scale, int RELU, int OUT_BF16) {
    __shared__ __align__(16) ushort smem[10240];
    ushort* As = smem;
    ushort* Bs = smem + 2048;
    float* red = (float*)smem;

    int tid = threadIdx.x;
    int w = tid >> 6, lane = tid & 63;
    int m0 = blockIdx.y * 16, n0 = blockIdx.x * 64;

    f32x4 acc[4] = {f32x4{0,0,0,0}, f32x4{0,0,0,0}, f32x4{0,0,0,0}, f32x4{0,0,0,0}};

    for (int k0 = 0; k0 < K; k0 += 128) {
        {
            int r = tid >> 4, k8 = tid & 15;
            short8v av = *reinterpret_cast<const short8v*>(&A[(m0 + r) * K + k0 + k8 * 8]);
            int dstb = r * 256 + ((k8 * 16) ^ ((r & 7) << 4));
            *reinterpret_cast<short8v*>((char*)As + dstb) = av;
        }
#pragma unroll
        for (int it = 0; it < 4; it++) {
            int idx = it * 256 + tid;
            int r = idx >> 4, k8 = idx & 15;
            short8v bv = *reinterpret_cast<const short8v*>(&Wt[(n0 + r) * K + k0 + k8 * 8]);
            int dstb = r * 256 + ((k8 * 16) ^ ((r & 7) << 4));
            *reinterpret_cast<short8v*>((char*)Bs + dstb) = bv;
        }
        __syncthreads();
        int kb = w * 64 + (lane >> 4) * 16;
        int arow = lane & 15;
        short8v a = *reinterpret_cast<const short8v*>(
            (char*)As + arow * 256 + (kb ^ ((arow & 7) << 4)));
#pragma unroll
        for (int nb = 0; nb < 4; nb++) {
            int nrow = nb * 16 + (lane & 15);
            short8v b = *reinterpret_cast<const short8v*>(
                (char*)Bs + nrow * 256 + (kb ^ ((nrow & 7) << 4)));
            acc[nb] = __builtin_amdgcn_mfma_f32_16x16x32_bf16(a, b, acc[nb], 0, 0, 0);
        }
        __syncthreads();
    }
    if (w > 0) {
        float* r0 = &red[((w - 1) * 64 + lane) * 16];
#pragma unroll
        for (int nb = 0; nb < 4; nb++)
            *reinterpret_cast<f32x4*>(&r0[nb * 4]) = acc[nb];
    }
    __syncthreads();
    if (w == 0) {
        const float* r0 = &red[lane * 16];
        const float* r1 = &red[(64 + lane) * 16];
        const float* r2 = &red[(128 + lane) * 16];
        int col = lane & 15;
#pragma unroll
        for (int nb = 0; nb < 4; nb++) {
            int n = n0 + nb * 16 + col;
            float bia = bias[n];
#pragma unroll
            for (int i = 0; i < 4; i++) {
                int idx = nb * 4 + i;
                int m = m0 + (lane >> 4) * 4 + i;
                float v = acc[nb][i] + r0[idx] + r1[idx] + r2[idx];
                v = (v + bia) * scale;
                if (RELU) v = fmaxf(v, 0.f);
                if (resid) v += resid[m * N + n];
                if (OUT_BF16) ((ushort*)out)[m * N + n] = f2bf(v);
                else          ((float*)out)[m * N + n] = v;
            }
        }
    }
}

template <int RELU, int OUT_BF16>
__global__ __launch_bounds__(256) void gemm_bf16(
    const ushort* __restrict__ A, const ushort* __restrict__ Wt,
    const float* __restrict__ bias, const float* __restrict__ resid,
    void* __restrict__ out, int N, int K, float scale) {
    gemm_mfma_body(A, Wt, bias, resid, out, N, K, scale, RELU, OUT_BF16);
}

__global__ __launch_bounds__(256) void qkv_bf16(
    const ushort* __restrict__ A,
    const ushort* __restrict__ Wqt, const float* __restrict__ bq, float* __restrict__ qo,
    const ushort* __restrict__ Wkt, const float* __restrict__ bk, float* __restrict__ ko,
    const ushort* __restrict__ Wvt, const float* __restrict__ bv, float* __restrict__ vo,
    float qscale) {
    int z = blockIdx.z;
    const ushort* W = (z == 0) ? Wqt : (z == 1) ? Wkt : Wvt;
    const float* bi = (z == 0) ? bq : (z == 1) ? bk : bv;
    float* o = (z == 0) ? qo : (z == 1) ? ko : vo;
    float sc = (z == 0) ? qscale : 1.f;
    gemm_mfma_body(A, W, bi, nullptr, o, DD, DD, sc, 0, 0);
}

// ---------------- fused attention v4 ----------------
// v3 + bond-row register prefetch + factorized RBF (2 exp2 per (q,k), 3 VALU/term)
__global__ __launch_bounds__(256, 3) void attn_kernel(
    const float* __restrict__ qbuf, const float* __restrict__ kbuf,
    const float* __restrict__ vbuf, const float* __restrict__ u,
    const float* __restrict__ v, const float* __restrict__ temb,
    const float* __restrict__ bond, const int* __restrict__ lengths,
    ushort* __restrict__ ctx) {
    __shared__ float KV[256 * 32];          // XOR swizzle: [k*32 + (dh ^ (k&31))]
    __shared__ float sc[QTILE][260];
    __shared__ float qu_s[QTILE][32], qv_s[QTILE][32];
    __shared__ float tq[QTILE];
    __shared__ float temb_s[32];

    int qt = blockIdx.x;
    int h  = blockIdx.y;
    int b  = blockIdx.z;
    int t  = threadIdx.x;
    int len = lengths[b];
    int q0 = qt * QTILE;

    for (int e = t; e < QTILE * 32; e += 256) {
        int q = e >> 5, dh = e & 31;
        float qs = qbuf[(b * TT + q0 + q) * DD + h * 32 + dh];
        qu_s[q][dh] = qs + u[h * 32 + dh];
        qv_s[q][dh] = qs + v[h * 32 + dh];
    }
    if (t < 32) temb_s[t] = (h >= 4) ? temb[b * 128 + (h - 4) * 32 + t] : 0.f;
    for (int e = t; e < 256 * 32; e += 256) {
        int k = e >> 5, dh = e & 31;
        KV[k * 32 + (dh ^ (k & 31))] = kbuf[(b * TT + k) * DD + h * 32 + dh];
    }

    // prefetch bond row (16 independent coalesced loads; always in-bounds)
    float bond_reg[QTILE];
    if (h < 4) {
        const float* brow = bond + (size_t)(b * TT + q0) * TT + t;
#pragma unroll
        for (int q = 0; q < QTILE; q++) bond_reg[q] = brow[q * TT];
    }
    __syncthreads();

    if (t < QTILE) {
        float a = 0.f;
#pragma unroll
        for (int j = 0; j < 32; j++) a += qv_s[t][j] * temb_s[j];
        tq[t] = a;
    }
    __syncthreads();

    // cache this thread's K row (k = t) into registers
    float kreg[32];
    {
        int kx = t & 31;
#pragma unroll
        for (int dh = 0; dh < 32; dh++) kreg[dh] = KV[t * 32 + (dh ^ kx)];
    }

    // ---- scores: thread t owns key k = t, loops q ----
    {
        int k = t;
        bool kvalid = k < len;
        float c0 = (float)(h * 32) * RBF_DELTA;
        for (int q = 0; q < QTILE; q++) {
            float s;
            if (!kvalid) {
                s = -1e18f;
            } else {
                const float* qur = qu_s[q];
                float accA = 0.f;
#pragma unroll
                for (int c = 0; c < 8; c++) {
                    float4 q4 = *reinterpret_cast<const float4*>(&qur[c * 4]);
                    accA = fmaf(q4.x, kreg[c * 4 + 0], accA);
                    accA = fmaf(q4.y, kreg[c * 4 + 1], accA);
                    accA = fmaf(q4.z, kreg[c * 4 + 2], accA);
                    accA = fmaf(q4.w, kreg[c * 4 + 3], accA);
                }
                float accB;
                if (h < 4) {
                    accB = 0.f;
                    if (q0 + q < len) {
                        float diff0 = bond_reg[q] - c0;
                        float tt = exp2f(RBF_NEGK * diff0 * diff0);
                        float m  = exp2f(RBF_M0A * diff0 + RBF_M0B);
                        const float* qvr = qv_s[q];
#pragma unroll
                        for (int c = 0; c < 8; c++) {
                            float4 q4 = *reinterpret_cast<const float4*>(&qvr[c * 4]);
                            accB = fmaf(q4.x, tt, accB); tt *= m; m *= RBF_RHO;
                            accB = fmaf(q4.y, tt, accB); tt *= m; m *= RBF_RHO;
                            accB = fmaf(q4.z, tt, accB); tt *= m; m *= RBF_RHO;
                            accB = fmaf(q4.w, tt, accB); tt *= m; m *= RBF_RHO;
                        }
                    }
                } else {
                    accB = tq[q];
                }
                s = accA + accB;
            }
            sc[q][t] = s;
        }
    }
    __syncthreads();

    // ---- softmax: 16 threads per row ----
    {
        int r = t >> 4, j = t & 15;
        float vals[16];
        float mx = -1e30f;
#pragma unroll
        for (int i = 0; i < 16; i++) {
            vals[i] = sc[r][j + 16 * i];
            mx = fmaxf(mx, vals[i]);
        }
        for (int off = 8; off > 0; off >>= 1) mx = fmaxf(mx, __shfl_xor(mx, off));
        float sum = 0.f;
#pragma unroll
        for (int i = 0; i < 16; i++) {
            float e = __expf(vals[i] - mx);
            vals[i] = e; sum += e;
        }
        for (int off = 8; off > 0; off >>= 1) sum += __shfl_xor(sum, off);
        float inv = 1.f / sum;
#pragma unroll
        for (int i = 0; i < 16; i++) sc[r][j + 16 * i] = vals[i] * inv;
    }
    // restage V over K (swizzled; no KV reader between barriers)
    for (int e = t; e < 256 * 32; e += 256) {
        int k2 = e >> 5, dh = e & 31;
        KV[k2 * 32 + (dh ^ (k2 & 31))] = vbuf[(b * TT + k2) * DD + h * 32 + dh];
    }
    __syncthreads();

    // ---- ctx = attn @ V ----
    {
        int dh = t & 31, qq = t >> 5;
#pragma unroll
        for (int rep = 0; rep < 2; rep++) {
            int q = qq + 8 * rep;
            float acc = 0.f;
#pragma unroll 8
            for (int kk = 0; kk < 256; kk += 4) {
                float4 s4 = *reinterpret_cast<const float4*>(&sc[q][kk]);
                acc = fmaf(s4.x, KV[(kk + 0) * 32 + (dh ^ ((kk + 0) & 31))], acc);
                acc = fmaf(s4.y, KV[(kk + 1) * 32 + (dh ^ ((kk + 1) & 31))], acc);
                acc = fmaf(s4.z, KV[(kk + 2) * 32 + (dh ^ ((kk + 2) & 31))], acc);
                acc = fmaf(s4.w, KV[(kk + 3) * 32 + (dh ^ ((kk + 3) & 31))], acc);
            }
            ctx[(b * TT + q0 + q) * DD + h * 32 + dh] = f2bf(acc);
        }
    }
}

// ---------------- host launcher ----------------
extern "C" void kernel_launch(void* const* d_in, const int* in_sizes, int n_in,
                              void* d_out, int out_size, void* d_ws, size_t ws_size,
                              hipStream_t stream) {
    const int*   src      = (const int*)  d_in[0];
    const int*   lengths  = (const int*)  d_in[1];
    const float* bond     = (const float*)d_in[2];
    const float* timestep = (const float*)d_in[3];
    const float* emb      = (const float*)d_in[4];
    const float* t_w1     = (const float*)d_in[5];
    const float* t_b1     = (const float*)d_in[6];
    const float* t_w2     = (const float*)d_in[7];
    const float* t_b2     = (const float*)d_in[8];
    const float* u        = (const float*)d_in[9];
    const float* v        = (const float*)d_in[10];
    const float* Wq       = (const float*)d_in[11];
    const float* bq       = (const float*)d_in[12];
    const float* Wk       = (const float*)d_in[13];
    const float* bk       = (const float*)d_in[14];
    const float* Wv       = (const float*)d_in[15];
    const float* bv       = (const float*)d_in[16];
    const float* Wo       = (const float*)d_in[17];
    const float* bo       = (const float*)d_in[18];
    const float* ln1_g    = (const float*)d_in[19];
    const float* ln1_b    = (const float*)d_in[20];
    const float* ln2_g    = (const float*)d_in[21];
    const float* ln2_b    = (const float*)d_in[22];
    const float* ff_w1    = (const float*)d_in[23];
    const float* ff_b1    = (const float*)d_in[24];
    const float* ff_w2    = (const float*)d_in[25];
    const float* ff_b2    = (const float*)d_in[26];
    const float* lnf_g    = (const float*)d_in[27];
    const float* lnf_b    = (const float*)d_in[28];

    float* ws   = (float*)d_ws;
    float* xbuf = ws;
    float* qbuf = xbuf + 524288;
    float* kbuf = qbuf + 524288;
    float* vbuf = kbuf + 524288;
    float* obuf = vbuf + 524288;
    float* temb = obuf + 524288;
    ushort* hbuf_bf  = (ushort*)(temb + 1024);
    ushort* cbuf_bf  = hbuf_bf + 524288;
    ushort* ffbuf_bf = cbuf_bf + 524288;
    ushort* wqt_bf   = ffbuf_bf + 2097152;
    ushort* wkt_bf   = wqt_bf + 262144;
    ushort* wvt_bf   = wkt_bf + 262144;
    ushort* wot_bf   = wvt_bf + 262144;
    ushort* ffw1t_bf = wot_bf + 262144;
    ushort* ffw2t_bf = ffw1t_bf + 1048576;

    dim3 tb(32, 8);
    transpose_bf16_kernel<<<dim3(8, 8, 4), tb, 0, stream>>>(Wq, wqt_bf, 256, 256, 65536);
    transpose_bf16_kernel<<<dim3(8, 8, 4), tb, 0, stream>>>(Wk, wkt_bf, 256, 256, 65536);
    transpose_bf16_kernel<<<dim3(8, 8, 4), tb, 0, stream>>>(Wv, wvt_bf, 256, 256, 65536);
    transpose_bf16_kernel<<<dim3(8, 8, 4), tb, 0, stream>>>(Wo, wot_bf, 256, 256, 65536);
    transpose_bf16_kernel<<<dim3(32, 8, 4), tb, 0, stream>>>(ff_w1, ffw1t_bf, 256, 1024, 262144);
    transpose_bf16_kernel<<<dim3(8, 32, 4), tb, 0, stream>>>(ff_w2, ffw2t_bf, 1024, 256, 262144);

    temb_kernel<<<8, 128, 0, stream>>>(timestep, t_w1, t_b1, t_w2, t_b2, temb);
    embed_kernel<<<2048, 256, 0, stream>>>(src, emb, xbuf);

    const float scale = 0.17677669529663687f;  // 1/sqrt(32)
    dim3 gqkv(4, 128, 3);
    dim3 g256(4, 128);
    dim3 g1024(16, 128);

    for (int l = 0; l < LL; l++) {
        ln_kernel<1><<<2048, 256, 0, stream>>>(xbuf, ln1_g + l * 256, ln1_b + l * 256, hbuf_bf);
        qkv_bf16<<<gqkv, 256, 0, stream>>>(hbuf_bf,
            wqt_bf + l * 65536, bq + l * 256, qbuf,
            wkt_bf + l * 65536, bk + l * 256, kbuf,
            wvt_bf + l * 65536, bv + l * 256, vbuf, scale);
        attn_kernel<<<dim3(16, 8, 8), 256, 0, stream>>>(qbuf, kbuf, vbuf, u, v, temb, bond, lengths, cbuf_bf);
        gemm_bf16<0, 0><<<g256, 256, 0, stream>>>(cbuf_bf, wot_bf + l * 65536, bo + l * 256, xbuf, obuf, 256, 256, 1.f);
        ln_kernel<1><<<2048, 256, 0, stream>>>(obuf, ln2_g + l * 256, ln2_b + l * 256, hbuf_bf);
        gemm_bf16<1, 1><<<g1024, 256, 0, stream>>>(hbuf_bf, ffw1t_bf + l * 262144, ff_b1 + l * 1024, nullptr, ffbuf_bf, 1024, 256, 1.f);
        gemm_bf16<0, 0><<<g256, 256, 0, stream>>>(ffbuf_bf, ffw2t_bf + l * 262144, ff_b2 + l * 256, obuf, xbuf, 256, 1024, 1.f);
    }
    ln_kernel<0><<<2048, 256, 0, stream>>>(xbuf, lnf_g, lnf_b, (float*)d_out);
}

// Round 14
// 526.594 us; speedup vs baseline: 1.4924x; 1.0073x over previous
//
#include <hip/hip_runtime.h>
#include <hip/hip_bf16.h>
#include <math.h>

#define BB 8
#define TT 256
#define DD 256
#define HH 8
#define DHH 32
#define LL 4
#define DFF 1024
#define QTILE 16

#define RBF_DELTA 0.05039370078740158f
#define RBF_NEGK -28.853900817779268f     // -20/ln2
#define RBF_M0A 2.9081851339f             // 2*(20/ln2)*DELTA
#define RBF_M0B -0.0732754690f            // -(20/ln2)*DELTA^2
#define RBF_RHO 0.9034077526f             // exp(-40*DELTA^2)

typedef __attribute__((ext_vector_type(8))) short short8v;
typedef __attribute__((ext_vector_type(4))) short short4v;
typedef __attribute__((ext_vector_type(4))) float f32x4;

__device__ __forceinline__ ushort f2bf(float x) {
    __hip_bfloat16 h = __float2bfloat16(x);
    return *reinterpret_cast<ushort*>(&h);
}
__device__ __forceinline__ float bf2f(uint u16) {   // low 16 bits hold bf16
    return __uint_as_float(u16 << 16);
}

// ---------------- transpose + convert: W f32 [K][N] -> Wt bf16 [N][K] -------
__global__ void transpose_bf16_kernel(const float* __restrict__ in, ushort* __restrict__ out,
                                      int K, int N, int lstride) {
    __shared__ float tile[32][33];
    int l = blockIdx.z;
    const float* W = in + (size_t)l * lstride;
    ushort* Wt = out + (size_t)l * lstride;
    int kb = blockIdx.y * 32, nb = blockIdx.x * 32;
    int tx = threadIdx.x, ty = threadIdx.y;
#pragma unroll
    for (int i = 0; i < 4; i++) {
        int r = ty + i * 8;
        tile[r][tx] = W[(kb + r) * N + nb + tx];
    }
    __syncthreads();
#pragma unroll
    for (int i = 0; i < 4; i++) {
        int r = ty + i * 8;
        Wt[(nb + r) * K + kb + tx] = f2bf(tile[tx][r]);
    }
}

// ---------------- temb ----------------
__global__ void temb_kernel(const float* __restrict__ timestep,
                            const float* __restrict__ t_w1, const float* __restrict__ t_b1,
                            const float* __restrict__ t_w2, const float* __restrict__ t_b2,
                            float* __restrict__ temb_out) {
    __shared__ float s0[128], s1[128];
    int b = blockIdx.x, j = threadIdx.x;
    float ts = timestep[b];
    const float LOG1E4 = 9.210340371976184f;
    if (j < 64) {
        float f = expf(-LOG1E4 * (float)j / 64.f);
        s0[j] = cosf(ts * f);
    } else {
        int i = j - 64;
        float f = expf(-LOG1E4 * (float)i / 64.f);
        s0[j] = sinf(ts * f);
    }
    __syncthreads();
    float acc = t_b1[j];
    for (int i = 0; i < 128; i++) acc += s0[i] * t_w1[i * 128 + j];
    acc = acc / (1.f + expf(-acc));
    s1[j] = acc;
    __syncthreads();
    float acc2 = t_b2[j];
    for (int i = 0; i < 128; i++) acc2 += s1[i] * t_w2[i * 128 + j];
    temb_out[b * 128 + j] = acc2;
}

// ---------------- embedding ----------------
__global__ void embed_kernel(const int* __restrict__ src, const float* __restrict__ emb,
                             float* __restrict__ x) {
    int r = blockIdx.x, d = threadIdx.x;
    x[r * DD + d] = emb[src[r] * DD + d];
}

// ---------------- LayerNorm ----------------
template <int OUT_BF16>
__global__ void ln_kernel(const float* __restrict__ in, const float* __restrict__ g,
                          const float* __restrict__ bta, void* __restrict__ out) {
    __shared__ float red[8];
    __shared__ float mv[2];
    int r = blockIdx.x, t = threadIdx.x;
    float v = in[r * DD + t];
    float s = v, s2 = v * v;
    for (int off = 32; off > 0; off >>= 1) {
        s += __shfl_xor(s, off);
        s2 += __shfl_xor(s2, off);
    }
    int w = t >> 6;
    if ((t & 63) == 0) { red[w] = s; red[4 + w] = s2; }
    __syncthreads();
    if (t == 0) {
        float S = red[0] + red[1] + red[2] + red[3];
        float S2 = red[4] + red[5] + red[6] + red[7];
        float m = S * (1.f / 256.f);
        float var = S2 * (1.f / 256.f) - m * m;
        mv[0] = m; mv[1] = rsqrtf(var + 1e-6f);
    }
    __syncthreads();
    float o = (v - mv[0]) * mv[1] * g[t] + bta[t];
    if (OUT_BF16) ((ushort*)out)[r * DD + t] = f2bf(o);
    else          ((float*)out)[r * DD + t] = o;
}

// ---------------- bf16 MFMA GEMM, 4-wave split-K (unchanged, verified) ------
__device__ __forceinline__ void gemm_mfma_body(
    const ushort* __restrict__ A, const ushort* __restrict__ Wt,
    const float* __restrict__ bias, const float* __restrict__ resid,
    void* __restrict__ out, int N, int K, float scale, int RELU, int OUT_BF16) {
    __shared__ __align__(16) ushort smem[10240];
    ushort* As = smem;
    ushort* Bs = smem + 2048;
    float* red = (float*)smem;

    int tid = threadIdx.x;
    int w = tid >> 6, lane = tid & 63;
    int m0 = blockIdx.y * 16, n0 = blockIdx.x * 64;

    f32x4 acc[4] = {f32x4{0,0,0,0}, f32x4{0,0,0,0}, f32x4{0,0,0,0}, f32x4{0,0,0,0}};

    for (int k0 = 0; k0 < K; k0 += 128) {
        {
            int r = tid >> 4, k8 = tid & 15;
            short8v av = *reinterpret_cast<const short8v*>(&A[(m0 + r) * K + k0 + k8 * 8]);
            int dstb = r * 256 + ((k8 * 16) ^ ((r & 7) << 4));
            *reinterpret_cast<short8v*>((char*)As + dstb) = av;
        }
#pragma unroll
        for (int it = 0; it < 4; it++) {
            int idx = it * 256 + tid;
            int r = idx >> 4, k8 = idx & 15;
            short8v bv = *reinterpret_cast<const short8v*>(&Wt[(n0 + r) * K + k0 + k8 * 8]);
            int dstb = r * 256 + ((k8 * 16) ^ ((r & 7) << 4));
            *reinterpret_cast<short8v*>((char*)Bs + dstb) = bv;
        }
        __syncthreads();
        int kb = w * 64 + (lane >> 4) * 16;
        int arow = lane & 15;
        short8v a = *reinterpret_cast<const short8v*>(
            (char*)As + arow * 256 + (kb ^ ((arow & 7) << 4)));
#pragma unroll
        for (int nb = 0; nb < 4; nb++) {
            int nrow = nb * 16 + (lane & 15);
            short8v b = *reinterpret_cast<const short8v*>(
                (char*)Bs + nrow * 256 + (kb ^ ((nrow & 7) << 4)));
            acc[nb] = __builtin_amdgcn_mfma_f32_16x16x32_bf16(a, b, acc[nb], 0, 0, 0);
        }
        __syncthreads();
    }
    if (w > 0) {
        float* r0 = &red[((w - 1) * 64 + lane) * 16];
#pragma unroll
        for (int nb = 0; nb < 4; nb++)
            *reinterpret_cast<f32x4*>(&r0[nb * 4]) = acc[nb];
    }
    __syncthreads();
    if (w == 0) {
        const float* r0 = &red[lane * 16];
        const float* r1 = &red[(64 + lane) * 16];
        const float* r2 = &red[(128 + lane) * 16];
        int col = lane & 15;
#pragma unroll
        for (int nb = 0; nb < 4; nb++) {
            int n = n0 + nb * 16 + col;
            float bia = bias[n];
#pragma unroll
            for (int i = 0; i < 4; i++) {
                int idx = nb * 4 + i;
                int m = m0 + (lane >> 4) * 4 + i;
                float v = acc[nb][i] + r0[idx] + r1[idx] + r2[idx];
                v = (v + bia) * scale;
                if (RELU) v = fmaxf(v, 0.f);
                if (resid) v += resid[m * N + n];
                if (OUT_BF16) ((ushort*)out)[m * N + n] = f2bf(v);
                else          ((float*)out)[m * N + n] = v;
            }
        }
    }
}

template <int RELU, int OUT_BF16>
__global__ __launch_bounds__(256) void gemm_bf16(
    const ushort* __restrict__ A, const ushort* __restrict__ Wt,
    const float* __restrict__ bias, const float* __restrict__ resid,
    void* __restrict__ out, int N, int K, float scale) {
    gemm_mfma_body(A, Wt, bias, resid, out, N, K, scale, RELU, OUT_BF16);
}

__global__ __launch_bounds__(256) void qkv_bf16(
    const ushort* __restrict__ A,
    const ushort* __restrict__ Wqt, const float* __restrict__ bq, float* __restrict__ qo,
    const ushort* __restrict__ Wkt, const float* __restrict__ bk, float* __restrict__ ko,
    const ushort* __restrict__ Wvt, const float* __restrict__ bv, float* __restrict__ vo,
    float qscale) {
    int z = blockIdx.z;
    const ushort* W = (z == 0) ? Wqt : (z == 1) ? Wkt : Wvt;
    const float* bi = (z == 0) ? bq : (z == 1) ? bk : bv;
    float* o = (z == 0) ? qo : (z == 1) ? ko : vo;
    float sc = (z == 0) ? qscale : 1.f;
    gemm_mfma_body(A, W, bi, nullptr, o, DD, DD, sc, 0, 0);
}

// ---------------- fused attention v5 ----------------
// K-row from global into regs (no K LDS); V packed bf16x2 in LDS (16KB);
// LDS ~37KB -> 4 blocks/CU, grid 1024 = fully resident. Dual-q scores for ILP.
__device__ __forceinline__ float score_one(
    const float* __restrict__ qur, const float* __restrict__ qvr,
    const float* kreg, float bondv, float c0, int h, bool qvalid, float tqv) {
    float a0 = 0.f, a1 = 0.f;
#pragma unroll
    for (int c = 0; c < 8; c += 2) {
        float4 x = *reinterpret_cast<const float4*>(&qur[c * 4]);
        float4 y = *reinterpret_cast<const float4*>(&qur[c * 4 + 4]);
        a0 = fmaf(x.x, kreg[c * 4 + 0], a0);
        a0 = fmaf(x.y, kreg[c * 4 + 1], a0);
        a0 = fmaf(x.z, kreg[c * 4 + 2], a0);
        a0 = fmaf(x.w, kreg[c * 4 + 3], a0);
        a1 = fmaf(y.x, kreg[c * 4 + 4], a1);
        a1 = fmaf(y.y, kreg[c * 4 + 5], a1);
        a1 = fmaf(y.z, kreg[c * 4 + 6], a1);
        a1 = fmaf(y.w, kreg[c * 4 + 7], a1);
    }
    float accA = a0 + a1;
    float accB;
    if (h < 4) {
        accB = 0.f;
        if (qvalid) {
            float diff0 = bondv - c0;
            float tt = exp2f(RBF_NEGK * diff0 * diff0);
            float m  = exp2f(RBF_M0A * diff0 + RBF_M0B);
#pragma unroll
            for (int c = 0; c < 8; c++) {
                float4 q4 = *reinterpret_cast<const float4*>(&qvr[c * 4]);
                accB = fmaf(q4.x, tt, accB); tt *= m; m *= RBF_RHO;
                accB = fmaf(q4.y, tt, accB); tt *= m; m *= RBF_RHO;
                accB = fmaf(q4.z, tt, accB); tt *= m; m *= RBF_RHO;
                accB = fmaf(q4.w, tt, accB); tt *= m; m *= RBF_RHO;
            }
        }
    } else {
        accB = tqv;
    }
    return accA + accB;
}

__global__ __launch_bounds__(256, 4) void attn_kernel(
    const float* __restrict__ qbuf, const float* __restrict__ kbuf,
    const float* __restrict__ vbuf, const float* __restrict__ u,
    const float* __restrict__ v, const float* __restrict__ temb,
    const float* __restrict__ bond, const int* __restrict__ lengths,
    ushort* __restrict__ ctx) {
    __shared__ uint  Vp[256 * 16];          // V packed: 2 bf16 per uint, row=16 uints
    __shared__ float sc[QTILE][260];
    __shared__ float qu_s[QTILE][32], qv_s[QTILE][32];
    __shared__ float tq[QTILE];
    __shared__ float temb_s[32];

    int qt = blockIdx.x;
    int h  = blockIdx.y;
    int b  = blockIdx.z;
    int t  = threadIdx.x;
    int len = lengths[b];
    int q0 = qt * QTILE;

    // issue K-row gather early (L2-resident; 8 independent dwordx4)
    float kreg[32];
    {
        const float* krow = &kbuf[(size_t)(b * TT + t) * DD + h * 32];
#pragma unroll
        for (int c = 0; c < 8; c++) {
            float4 k4 = *reinterpret_cast<const float4*>(&krow[c * 4]);
            kreg[c * 4 + 0] = k4.x; kreg[c * 4 + 1] = k4.y;
            kreg[c * 4 + 2] = k4.z; kreg[c * 4 + 3] = k4.w;
        }
    }
    // bond row prefetch
    float bond_reg[QTILE];
    if (h < 4) {
        const float* brow = bond + (size_t)(b * TT + q0) * TT + t;
#pragma unroll
        for (int q = 0; q < QTILE; q++) bond_reg[q] = brow[q * TT];
    }

    // stage qu/qv (+u,+v)
    for (int e = t; e < QTILE * 32; e += 256) {
        int q = e >> 5, dh = e & 31;
        float qs = qbuf[(b * TT + q0 + q) * DD + h * 32 + dh];
        qu_s[q][dh] = qs + u[h * 32 + dh];
        qv_s[q][dh] = qs + v[h * 32 + dh];
    }
    if (t < 32) temb_s[t] = (h >= 4) ? temb[b * 128 + (h - 4) * 32 + t] : 0.f;
    // stage V packed bf16x2
#pragma unroll
    for (int i = 0; i < 16; i++) {
        int e = i * 256 + t;
        int k = e >> 4, dh2 = e & 15;
        float2 v2 = *reinterpret_cast<const float2*>(&vbuf[(size_t)(b * TT + k) * DD + h * 32 + dh2 * 2]);
        Vp[e] = (uint)f2bf(v2.x) | ((uint)f2bf(v2.y) << 16);
    }
    __syncthreads();

    if (t < QTILE) {
        float a = 0.f;
#pragma unroll
        for (int j = 0; j < 32; j++) a += qv_s[t][j] * temb_s[j];
        tq[t] = a;
    }
    __syncthreads();

    // ---- scores: thread t owns key k=t; 2 q per iteration for ILP ----
    {
        float c0 = (float)(h * 32) * RBF_DELTA;
        if (t >= len) {
#pragma unroll
            for (int q = 0; q < QTILE; q++) sc[q][t] = -1e18f;
        } else {
            for (int q = 0; q < QTILE; q += 2) {
                bool qv0 = (q0 + q) < len, qv1 = (q0 + q + 1) < len;
                float s0 = score_one(qu_s[q],     qv_s[q],     kreg, bond_reg[q],     c0, h, qv0, tq[q]);
                float s1 = score_one(qu_s[q + 1], qv_s[q + 1], kreg, bond_reg[q + 1], c0, h, qv1, tq[q + 1]);
                sc[q][t] = s0;
                sc[q + 1][t] = s1;
            }
        }
    }
    __syncthreads();

    // ---- softmax: 16 threads per row ----
    {
        int r = t >> 4, j = t & 15;
        float vals[16];
        float mx = -1e30f;
#pragma unroll
        for (int i = 0; i < 16; i++) {
            vals[i] = sc[r][j + 16 * i];
            mx = fmaxf(mx, vals[i]);
        }
        for (int off = 8; off > 0; off >>= 1) mx = fmaxf(mx, __shfl_xor(mx, off));
        float sum = 0.f;
#pragma unroll
        for (int i = 0; i < 16; i++) {
            float e = __expf(vals[i] - mx);
            vals[i] = e; sum += e;
        }
        for (int off = 8; off > 0; off >>= 1) sum += __shfl_xor(sum, off);
        float inv = 1.f / sum;
#pragma unroll
        for (int i = 0; i < 16; i++) sc[r][j + 16 * i] = vals[i] * inv;
    }
    __syncthreads();

    // ---- ctx = attn @ V : thread owns (q = t>>4, dh pair = t&15) ----
    {
        int dh2 = t & 15, q = t >> 4;
        float acc0 = 0.f, acc1 = 0.f;
#pragma unroll 8
        for (int kk = 0; kk < 256; kk += 4) {
            float4 s4 = *reinterpret_cast<const float4*>(&sc[q][kk]);
            uint p0 = Vp[(kk + 0) * 16 + dh2];
            uint p1 = Vp[(kk + 1) * 16 + dh2];
            uint p2 = Vp[(kk + 2) * 16 + dh2];
            uint p3 = Vp[(kk + 3) * 16 + dh2];
            acc0 = fmaf(s4.x, bf2f(p0 & 0xffff), acc0);
            acc1 = fmaf(s4.x, __uint_as_float(p0 & 0xffff0000u), acc1);
            acc0 = fmaf(s4.y, bf2f(p1 & 0xffff), acc0);
            acc1 = fmaf(s4.y, __uint_as_float(p1 & 0xffff0000u), acc1);
            acc0 = fmaf(s4.z, bf2f(p2 & 0xffff), acc0);
            acc1 = fmaf(s4.z, __uint_as_float(p2 & 0xffff0000u), acc1);
            acc0 = fmaf(s4.w, bf2f(p3 & 0xffff), acc0);
            acc1 = fmaf(s4.w, __uint_as_float(p3 & 0xffff0000u), acc1);
        }
        ushort2 o;
        o.x = f2bf(acc0);
        o.y = f2bf(acc1);
        *reinterpret_cast<ushort2*>(&ctx[(size_t)(b * TT + q0 + q) * DD + h * 32 + dh2 * 2]) = o;
    }
}

// ---------------- host launcher ----------------
extern "C" void kernel_launch(void* const* d_in, const int* in_sizes, int n_in,
                              void* d_out, int out_size, void* d_ws, size_t ws_size,
                              hipStream_t stream) {
    const int*   src      = (const int*)  d_in[0];
    const int*   lengths  = (const int*)  d_in[1];
    const float* bond     = (const float*)d_in[2];
    const float* timestep = (const float*)d_in[3];
    const float* emb      = (const float*)d_in[4];
    const float* t_w1     = (const float*)d_in[5];
    const float* t_b1     = (const float*)d_in[6];
    const float* t_w2     = (const float*)d_in[7];
    const float* t_b2     = (const float*)d_in[8];
    const float* u        = (const float*)d_in[9];
    const float* v        = (const float*)d_in[10];
    const float* Wq       = (const float*)d_in[11];
    const float* bq       = (const float*)d_in[12];
    const float* Wk       = (const float*)d_in[13];
    const float* bk       = (const float*)d_in[14];
    const float* Wv       = (const float*)d_in[15];
    const float* bv       = (const float*)d_in[16];
    const float* Wo       = (const float*)d_in[17];
    const float* bo       = (const float*)d_in[18];
    const float* ln1_g    = (const float*)d_in[19];
    const float* ln1_b    = (const float*)d_in[20];
    const float* ln2_g    = (const float*)d_in[21];
    const float* ln2_b    = (const float*)d_in[22];
    const float* ff_w1    = (const float*)d_in[23];
    const float* ff_b1    = (const float*)d_in[24];
    const float* ff_w2    = (const float*)d_in[25];
    const float* ff_b2    = (const float*)d_in[26];
    const float* lnf_g    = (const float*)d_in[27];
    const float* lnf_b    = (const float*)d_in[28];

    float* ws   = (float*)d_ws;
    float* xbuf = ws;
    float* qbuf = xbuf + 524288;
    float* kbuf = qbuf + 524288;
    float* vbuf = kbuf + 524288;
    float* obuf = vbuf + 524288;
    float* temb = obuf + 524288;
    ushort* hbuf_bf  = (ushort*)(temb + 1024);
    ushort* cbuf_bf  = hbuf_bf + 524288;
    ushort* ffbuf_bf = cbuf_bf + 524288;
    ushort* wqt_bf   = ffbuf_bf + 2097152;
    ushort* wkt_bf   = wqt_bf + 262144;
    ushort* wvt_bf   = wkt_bf + 262144;
    ushort* wot_bf   = wvt_bf + 262144;
    ushort* ffw1t_bf = wot_bf + 262144;
    ushort* ffw2t_bf = ffw1t_bf + 1048576;

    dim3 tb(32, 8);
    transpose_bf16_kernel<<<dim3(8, 8, 4), tb, 0, stream>>>(Wq, wqt_bf, 256, 256, 65536);
    transpose_bf16_kernel<<<dim3(8, 8, 4), tb, 0, stream>>>(Wk, wkt_bf, 256, 256, 65536);
    transpose_bf16_kernel<<<dim3(8, 8, 4), tb, 0, stream>>>(Wv, wvt_bf, 256, 256, 65536);
    transpose_bf16_kernel<<<dim3(8, 8, 4), tb, 0, stream>>>(Wo, wot_bf, 256, 256, 65536);
    transpose_bf16_kernel<<<dim3(32, 8, 4), tb, 0, stream>>>(ff_w1, ffw1t_bf, 256, 1024, 262144);
    transpose_bf16_kernel<<<dim3(8, 32, 4), tb, 0, stream>>>(ff_w2, ffw2t_bf, 1024, 256, 262144);

    temb_kernel<<<8, 128, 0, stream>>>(timestep, t_w1, t_b1, t_w2, t_b2, temb);
    embed_kernel<<<2048, 256, 0, stream>>>(src, emb, xbuf);

    const float scale = 0.17677669529663687f;  // 1/sqrt(32)
    dim3 gqkv(4, 128, 3);
    dim3 g256(4, 128);
    dim3 g1024(16, 128);

    for (int l = 0; l < LL; l++) {
        ln_kernel<1><<<2048, 256, 0, stream>>>(xbuf, ln1_g + l * 256, ln1_b + l * 256, hbuf_bf);
        qkv_bf16<<<gqkv, 256, 0, stream>>>(hbuf_bf,
            wqt_bf + l * 65536, bq + l * 256, qbuf,
            wkt_bf + l * 65536, bk + l * 256, kbuf,
            wvt_bf + l * 65536, bv + l * 256, vbuf, scale);
        attn_kernel<<<dim3(16, 8, 8), 256, 0, stream>>>(qbuf, kbuf, vbuf, u, v, temb, bond, lengths, cbuf_bf);
        gemm_bf16<0, 0><<<g256, 256, 0, stream>>>(cbuf_bf, wot_bf + l * 65536, bo + l * 256, xbuf, obuf, 256, 256, 1.f);
        ln_kernel<1><<<2048, 256, 0, stream>>>(obuf, ln2_g + l * 256, ln2_b + l * 256, hbuf_bf);
        gemm_bf16<1, 1><<<g1024, 256, 0, stream>>>(hbuf_bf, ffw1t_bf + l * 262144, ff_b1 + l * 1024, nullptr, ffbuf_bf, 1024, 256, 1.f);
        gemm_bf16<0, 0><<<g256, 256, 0, stream>>>(ffbuf_bf, ffw2t_bf + l * 262144, ff_b2 + l * 256, obuf, xbuf, 256, 1024, 1.f);
    }
    ln_kernel<0><<<2048, 256, 0, stream>>>(xbuf, lnf_g, lnf_b, (float*)d_out);
}